// Round 10
// baseline (371.486 us; speedup 1.0000x reference)
//
#include <hip/hip_runtime.h>
#include <hip/hip_bf16.h>
#include <cstdint>
#include <cstddef>

#define B_ 4
#define T_ 2048
#define C_ 768
#define H_ 12
#define D_ 64
#define FF_ 3072

typedef __attribute__((ext_vector_type(4))) float f32x4;
typedef __attribute__((ext_vector_type(8))) short s16x8;
typedef __attribute__((ext_vector_type(4))) short s16x4;

static __device__ __forceinline__ short f2bf(float f) {
  union { float fv; unsigned u; } v; v.fv = f;
  unsigned r = v.u + 0x7FFFu + ((v.u >> 16) & 1u);  // RNE
  return (short)(r >> 16);
}

static __device__ __forceinline__ unsigned pkbf2(float a, float b) {
  __hip_bfloat162 h = __float22bfloat162_rn(make_float2(a, b));  // v_cvt_pk_bf16_f32
  union { __hip_bfloat162 h2; unsigned u; } v; v.h2 = h;
  return v.u;
}

// ---------- weight convert+transpose: in[K,N] f32 -> out[N,K] bf16 ----------
__global__ __launch_bounds__(256) void wconv(const float* __restrict__ in,
                                             short* __restrict__ out,
                                             int K, int N) {
  __shared__ float tile[32][33];
  int tk = blockIdx.x * 32, tn = blockIdx.y * 32;
  int lx = threadIdx.x & 31, ly = threadIdx.x >> 5;
#pragma unroll
  for (int i = 0; i < 4; ++i)
    tile[ly + i * 8][lx] = in[(size_t)(tk + ly + i * 8) * N + tn + lx];
  __syncthreads();
#pragma unroll
  for (int i = 0; i < 4; ++i)
    out[(size_t)(tn + ly + i * 8) * K + tk + lx] = f2bf(tile[lx][ly + i * 8]);
}

// ---------- layernorm: x[rows,768] f32 -> bf16 ----------
__global__ __launch_bounds__(256) void ln_kernel(const float* __restrict__ x,
                                                 const float* __restrict__ w,
                                                 const float* __restrict__ b,
                                                 short* __restrict__ out) {
  int row = blockIdx.x, tid = threadIdx.x;
  const float* xr = x + (size_t)row * 768;
  float v0 = xr[tid], v1 = xr[tid + 256], v2 = xr[tid + 512];
  float s = v0 + v1 + v2;
#pragma unroll
  for (int o = 32; o > 0; o >>= 1) s += __shfl_down(s, o);
  __shared__ float r1[4], r2[4];
  if ((tid & 63) == 0) r1[tid >> 6] = s;
  __syncthreads();
  float mean = (r1[0] + r1[1] + r1[2] + r1[3]) * (1.f / 768.f);
  float d0 = v0 - mean, d1 = v1 - mean, d2 = v2 - mean;
  float q = d0 * d0 + d1 * d1 + d2 * d2;
#pragma unroll
  for (int o = 32; o > 0; o >>= 1) q += __shfl_down(q, o);
  if ((tid & 63) == 0) r2[tid >> 6] = q;
  __syncthreads();
  float var = (r2[0] + r2[1] + r2[2] + r2[3]) * (1.f / 768.f);
  float rstd = rsqrtf(var + 1e-5f);
  short* orow = out + (size_t)row * 768;
  orow[tid]       = f2bf(d0 * rstd * w[tid]       + b[tid]);
  orow[tid + 256] = f2bf(d1 * rstd * w[tid + 256] + b[tid + 256]);
  orow[tid + 512] = f2bf(d2 * rstd * w[tid + 512] + b[tid + 512]);
}

// ---------- GEMM: C[M,N] = A[M,K](bf16) * Bt[N,K](bf16)^T + bias, fused epilogues ----------
// MODE 0: qkv scatter (bias, q*=0.125*log2e for exp2-softmax); Q,K -> [B,H,T,D];
//         V -> TRANSPOSED [B,H,D,T]
// MODE 1/3: bias + residual(res f32) -> f32 out
// MODE 2: bias + relu -> bf16 out
template <int MODE>
__global__ __launch_bounds__(256) void gemm_bt(
    const short* __restrict__ A, const short* __restrict__ Bt,
    const float* __restrict__ bias, const float* __restrict__ res,
    void* __restrict__ out,
    short* __restrict__ dq, short* __restrict__ dk, short* __restrict__ dv,
    int M, int N, int K) {
  __shared__ short As[128 * 32];
  __shared__ short Bs[128 * 32];
  int tid = threadIdx.x;
  int lane = tid & 63;
  int wm = tid >> 7;
  int wn = (tid >> 6) & 1;
  const short* Ab = A + (size_t)blockIdx.x * 128 * K;
  const short* Bb = Bt + (size_t)blockIdx.y * 128 * K;
  f32x4 acc[4][4] = {};
  int i15 = lane & 15, g8 = (lane >> 4) << 3;
  int nk = K >> 5;
  for (int kt = 0; kt < nk; ++kt) {
    int kof = kt << 5;
#pragma unroll
    for (int i = 0; i < 2; ++i) {
      int s = tid + i * 256;
      int row = s >> 2, kk = (s & 3) << 3;
      __builtin_amdgcn_global_load_lds(
          (const __attribute__((address_space(1))) unsigned*)(Ab + (size_t)row * K + kof + kk),
          (__attribute__((address_space(3))) unsigned*)(As + s * 8), 16, 0, 0);
      __builtin_amdgcn_global_load_lds(
          (const __attribute__((address_space(1))) unsigned*)(Bb + (size_t)row * K + kof + kk),
          (__attribute__((address_space(3))) unsigned*)(Bs + s * 8), 16, 0, 0);
    }
    __syncthreads();
    s16x8 af[4], bfr[4];
#pragma unroll
    for (int m = 0; m < 4; ++m)
      af[m] = *(const s16x8*)(As + (wm * 64 + m * 16 + i15) * 32 + g8);
#pragma unroll
    for (int n = 0; n < 4; ++n)
      bfr[n] = *(const s16x8*)(Bs + (wn * 64 + n * 16 + i15) * 32 + g8);
#pragma unroll
    for (int m = 0; m < 4; ++m)
#pragma unroll
      for (int n = 0; n < 4; ++n)
        acc[m][n] = __builtin_amdgcn_mfma_f32_16x16x32_bf16(af[m], bfr[n], acc[m][n], 0, 0, 0);
    __syncthreads();
  }
  int row0 = blockIdx.x * 128 + wm * 64;
  int col0 = blockIdx.y * 128 + wn * 64;
  int g4 = (lane >> 4) << 2;
#pragma unroll
  for (int m = 0; m < 4; ++m) {
#pragma unroll
    for (int n = 0; n < 4; ++n) {
      int col = col0 + n * 16 + i15;
      float bv = bias[col];
      float v4[4];
#pragma unroll
      for (int r = 0; r < 4; ++r) v4[r] = acc[m][n][r] + bv;
      int rbase = row0 + m * 16 + g4;
      if constexpr (MODE == 0) {
        int sect = col / 768;            // 0=q 1=k 2=v
        int wi = col - sect * 768;
        int hh = wi >> 6, dd = wi & 63;
        int bb = rbase >> 11, tt = rbase & 2047;
        if (sect == 2) {
          s16x4 o4;
#pragma unroll
          for (int r = 0; r < 4; ++r) o4[r] = f2bf(v4[r]);
          *(s16x4*)(dv + ((size_t)(bb * H_ + hh) * D_ + dd) * T_ + tt) = o4;
        } else {
          short* dst = (sect == 0 ? dq : dk) + ((size_t)(bb * H_ + hh) * T_ + tt) * D_ + dd;
          float sc = sect == 0 ? 0.18033688f : 1.f;   // 0.125 * log2(e)
#pragma unroll
          for (int r = 0; r < 4; ++r) dst[(size_t)r * D_] = f2bf(v4[r] * sc);
        }
      } else if constexpr (MODE == 2) {
#pragma unroll
        for (int r = 0; r < 4; ++r)
          ((short*)out)[(size_t)(rbase + r) * N + col] = f2bf(v4[r] > 0.f ? v4[r] : 0.f);
      } else {
#pragma unroll
        for (int r = 0; r < 4; ++r)
          ((float*)out)[(size_t)(rbase + r) * N + col] = v4[r] + res[(size_t)(rbase + r) * N + col];
      }
    }
  }
}

// ---------- causal flash attention: LDS-staged, DMA, tile-parity split ----------
// 768 blocks (3/CU, all resident) x 256 thr (4 waves). Block = 64-q-row pair
// (p, 31-p) of one head -> uniform 33 tiles of 64 keys. Per tile: 16KB K+V
// staged once via global_load_lds (contiguous DMA, no VGPR dest, no address
// divergence - R2-R9's per-wave scattered global loads were the ~650cyc/trip
// throughput pin). Double-buffered; one barrier/tile (m97 structure).
// Tile-parity split: waves{0,1} compute even tiles, {2,3} odd -> each staged
// tile read by 2 waves (halves LDS reads); exp2-linear partials merged via
// one LDS combine per sub. XOR chunk-swizzle f(r)=2(r&7)+bit3(r) makes both
// QK (perm'd-row) and PV LDS reads 2-way = conflict-free.
// Q/K [B,H,T,D] (Q pre-scaled 0.125*log2e), VT [B,H,D,T] bf16 -> Ob [B,T,C].
__global__ __launch_bounds__(256) void attn_kernel(const short* __restrict__ Qb,
                                                   const short* __restrict__ Kb,
                                                   const short* __restrict__ VTb,
                                                   short* __restrict__ Ob) {
  __shared__ short KsT[2][4096];   // [buf][64 keys][64 d] swizzled
  __shared__ short VsT[2][4096];   // [buf][64 d][64 keys] swizzled
  __shared__ float comb[2][64][34];
  int i = blockIdx.x;
  int c = i & 7, j = i >> 3;
  int p = j & 15, gy = j >> 4;         // pair [0,16), head-group [0,6)
  int bh = c + (gy << 3);              // XCD(i)=i%8=c=bh%8: 6 heads/XCD in L2
  int bb = bh / H_, hh = bh - bb * H_;
  int tid = threadIdx.x, lane = tid & 63, wv = tid >> 6;
  int rhalf = wv & 1;                  // row half of the 64-row q-block
  int par = wv >> 1;                   // tile parity this wave computes
  const short* Qp = Qb + (size_t)bh * T_ * D_;
  const short* Kp = Kb + (size_t)bh * T_ * D_;
  const short* Vp = VTb + (size_t)bh * D_ * T_;
  int i15 = lane & 15, g = lane >> 4, g8 = g << 3;
  int keyA0 = ((i15 >> 2) << 3) + (i15 & 3);  // perm: A-row i -> key (i/4)*8+i%4
  int keyB0 = keyA0 + 4;
  int fA = ((keyA0 & 7) * 2 + ((keyA0 >> 3) & 1)) & 7;
  int fB = ((keyB0 & 7) * 2 + ((keyB0 >> 3) & 1)) & 7;
  int fV = ((i15 & 7) * 2 + ((i15 >> 3) & 1)) & 7;
  int offA0 = keyA0 * 64 + ((g ^ fA) << 3);
  int offB0 = keyB0 * 64 + ((g ^ fB) << 3);
  int offV0 = i15 * 64 + ((g ^ fV) << 3);
  int n0 = p + 1;                      // tiles for sub0; sub1 has 32-p; total 33
  int qb0 = p << 6, qb1 = (31 - p) << 6;

  s16x8 qf[2][2];
  f32x4 oacc[2][4] = {};
  float lsum[2] = {0.f, 0.f};

  auto loadQ = [&](int qb) {
#pragma unroll
    for (int s = 0; s < 2; ++s) {
      int qrow = qb + rhalf * 32 + s * 16 + i15;
      qf[s][0] = *(const s16x8*)(Qp + (size_t)qrow * D_ + g8);
      qf[s][1] = *(const s16x8*)(Qp + (size_t)qrow * D_ + 32 + g8);
    }
  };
  auto stage = [&](int buf, int k0) {
#pragma unroll
    for (int q = 0; q < 2; ++q) {
      int m = tid + q * 256;
      int r = m >> 3, cd = m & 7;
      int cs = cd ^ (((r & 7) * 2 + ((r >> 3) & 1)) & 7);  // inverse swizzle on SOURCE
      __builtin_amdgcn_global_load_lds(
          (const __attribute__((address_space(1))) unsigned*)(Kp + (size_t)(k0 + r) * D_ + (cs << 3)),
          (__attribute__((address_space(3))) unsigned*)(&KsT[buf][m * 8]), 16, 0, 0);
      __builtin_amdgcn_global_load_lds(
          (const __attribute__((address_space(1))) unsigned*)(Vp + (size_t)r * T_ + k0 + (cs << 3)),
          (__attribute__((address_space(3))) unsigned*)(&VsT[buf][m * 8]), 16, 0, 0);
    }
  };
  auto compute = [&](int buf, int k0, bool last, int qb) {
    const short* KB = &KsT[buf][0];
    const short* VB = &VsT[buf][0];
#pragma unroll
    for (int ks = 0; ks < 2; ++ks) {
      s16x8 ka0 = *(const s16x8*)(KB + (ks << 11) + offA0);
      s16x8 ka1 = *(const s16x8*)(KB + (ks << 11) + (offA0 ^ 32));
      s16x8 kb0 = *(const s16x8*)(KB + (ks << 11) + offB0);
      s16x8 kb1 = *(const s16x8*)(KB + (ks << 11) + (offB0 ^ 32));
      int vo = offV0 ^ (ks << 5);
      s16x8 vf0 = *(const s16x8*)(VB + vo);
      s16x8 vf1 = *(const s16x8*)(VB + 1024 + vo);
      s16x8 vf2 = *(const s16x8*)(VB + 2048 + vo);
      s16x8 vf3 = *(const s16x8*)(VB + 3072 + vo);
      int kb = k0 + (ks << 5) + g8;
#pragma unroll
      for (int s = 0; s < 2; ++s) {
        f32x4 sA = {}, sB = {};
        __builtin_amdgcn_s_setprio(1);
        sA = __builtin_amdgcn_mfma_f32_16x16x32_bf16(ka0, qf[s][0], sA, 0, 0, 0);
        sA = __builtin_amdgcn_mfma_f32_16x16x32_bf16(ka1, qf[s][1], sA, 0, 0, 0);
        sB = __builtin_amdgcn_mfma_f32_16x16x32_bf16(kb0, qf[s][0], sB, 0, 0, 0);
        sB = __builtin_amdgcn_mfma_f32_16x16x32_bf16(kb1, qf[s][1], sB, 0, 0, 0);
        __builtin_amdgcn_s_setprio(0);
        int qrow = qb + rhalf * 32 + s * 16 + i15;
        float sa[8];
        if (last) {
#pragma unroll
          for (int r = 0; r < 4; ++r) {
            sa[r]     = (kb + r     <= qrow) ? sA[r] : -1e30f;
            sa[4 + r] = (kb + 4 + r <= qrow) ? sB[r] : -1e30f;
          }
        } else {
#pragma unroll
          for (int r = 0; r < 4; ++r) { sa[r] = sA[r]; sa[4 + r] = sB[r]; }
        }
        float pv[8];
        float ps = 0.f;
#pragma unroll
        for (int r = 0; r < 8; ++r) {
          pv[r] = exp2f(sa[r]);
          ps += pv[r];
        }
        lsum[s] += ps;
        union { unsigned u[4]; s16x8 v; } pf;
        pf.u[0] = pkbf2(pv[0], pv[1]);
        pf.u[1] = pkbf2(pv[2], pv[3]);
        pf.u[2] = pkbf2(pv[4], pv[5]);
        pf.u[3] = pkbf2(pv[6], pv[7]);
        __builtin_amdgcn_s_setprio(1);
        oacc[s][0] = __builtin_amdgcn_mfma_f32_16x16x32_bf16(vf0, pf.v, oacc[s][0], 0, 0, 0);
        oacc[s][1] = __builtin_amdgcn_mfma_f32_16x16x32_bf16(vf1, pf.v, oacc[s][1], 0, 0, 0);
        oacc[s][2] = __builtin_amdgcn_mfma_f32_16x16x32_bf16(vf2, pf.v, oacc[s][2], 0, 0, 0);
        oacc[s][3] = __builtin_amdgcn_mfma_f32_16x16x32_bf16(vf3, pf.v, oacc[s][3], 0, 0, 0);
        __builtin_amdgcn_s_setprio(0);
      }
    }
  };
  auto finalize = [&](int qb) {
    if (par == 1) {
      float* dst = &comb[rhalf][lane][0];
#pragma unroll
      for (int s = 0; s < 2; ++s)
#pragma unroll
        for (int mt = 0; mt < 4; ++mt)
#pragma unroll
          for (int r = 0; r < 4; ++r) dst[s * 16 + mt * 4 + r] = oacc[s][mt][r];
      dst[32] = lsum[0];
      dst[33] = lsum[1];
    }
    __syncthreads();
    if (par == 0) {
      const float* src = &comb[rhalf][lane][0];
#pragma unroll
      for (int s = 0; s < 2; ++s)
#pragma unroll
        for (int mt = 0; mt < 4; ++mt)
#pragma unroll
          for (int r = 0; r < 4; ++r) oacc[s][mt][r] += src[s * 16 + mt * 4 + r];
      lsum[0] += src[32];
      lsum[1] += src[33];
#pragma unroll
      for (int s = 0; s < 2; ++s) {
        float l = lsum[s];
        l += __shfl_xor(l, 16);
        l += __shfl_xor(l, 32);
        float inv = 1.f / l;
        int qrow = qb + rhalf * 32 + s * 16 + i15;
        short* op = Ob + ((size_t)(bb * T_ + qrow)) * C_ + hh * D_ + (g << 2);
#pragma unroll
        for (int mt = 0; mt < 4; ++mt) {
          s16x4 o4;
#pragma unroll
          for (int r = 0; r < 4; ++r) o4[r] = f2bf(oacc[s][mt][r] * inv);
          *(s16x4*)(op + mt * 16) = o4;
        }
      }
    }
#pragma unroll
    for (int s = 0; s < 2; ++s) {
#pragma unroll
      for (int mt = 0; mt < 4; ++mt) oacc[s][mt] = f32x4{0.f, 0.f, 0.f, 0.f};
      lsum[s] = 0.f;
    }
  };

  loadQ(qb0);
  stage(0, 0);
  __syncthreads();
  int cur = 0;
#pragma unroll 1
  for (int t = 0; t < 33; ++t) {
    if (t + 1 < 33) {
      int nk0 = ((t + 1 < n0) ? (t + 1) : (t + 1 - n0)) << 6;
      stage(cur ^ 1, nk0);
    }
    int sub = (t >= n0) ? 1 : 0;
    int kt = sub ? t - n0 : t;
    bool last = sub ? (t == 32) : (t == n0 - 1);
    int qb = sub ? qb1 : qb0;
    if ((kt & 1) == par) compute(cur, kt << 6, last, qb);
    if (t == n0 - 1) {      // sub0 done for all waves (block-uniform)
      finalize(qb0);
      loadQ(qb1);
    }
    __syncthreads();
    cur ^= 1;
  }
  finalize(qb1);
}

extern "C" void kernel_launch(void* const* d_in, const int* in_sizes, int n_in,
                              void* d_out, int out_size, void* d_ws, size_t ws_size,
                              hipStream_t stream) {
  const float* x     = (const float*)d_in[0];
  const float* ln1_w = (const float*)d_in[1];
  const float* ln1_b = (const float*)d_in[2];
  const float* qkv_w = (const float*)d_in[3];
  const float* qkv_b = (const float*)d_in[4];
  const float* out_w = (const float*)d_in[5];
  const float* out_b = (const float*)d_in[6];
  const float* ln2_w = (const float*)d_in[7];
  const float* ln2_b = (const float*)d_in[8];
  const float* ff1_w = (const float*)d_in[9];
  const float* ff1_b = (const float*)d_in[10];
  const float* ff2_w = (const float*)d_in[11];
  const float* ff2_b = (const float*)d_in[12];

  char* ws = (char*)d_ws;
  short* Wqkv = (short*)(ws + 0);                       // [2304,768]
  short* Wout = (short*)(ws + 3538944);                 // [768,768]
  short* Wff1 = (short*)(ws + 4718592);                 // [3072,768]
  short* Wff2 = (short*)(ws + 9437184);                 // [768,3072]
  short* Hbuf = (short*)(ws + 14155776);                // [8192,768] bf16
  short* Qb   = (short*)(ws + 26738688);                // [B,H,T,D] bf16
  short* Kb   = Qb + 6291456;
  short* VT   = Kb + 6291456;                           // [B,H,D,T] bf16 (V stored transposed)
  short* Ob   = VT + 6291456;                           // [B,T,C] bf16
  short* FFH  = Qb;                                     // alias: [8192,3072] bf16 (Q/K/V/O dead)
  float* xout = (float*)d_out;                          // also x1 residual buffer

  wconv<<<dim3(24, 72), 256, 0, stream>>>(qkv_w, Wqkv, 768, 2304);
  wconv<<<dim3(24, 24), 256, 0, stream>>>(out_w, Wout, 768, 768);
  wconv<<<dim3(24, 96), 256, 0, stream>>>(ff1_w, Wff1, 768, 3072);
  wconv<<<dim3(96, 24), 256, 0, stream>>>(ff2_w, Wff2, 3072, 768);

  ln_kernel<<<8192, 256, 0, stream>>>(x, ln1_w, ln1_b, Hbuf);
  gemm_bt<0><<<dim3(64, 18), 256, 0, stream>>>(Hbuf, Wqkv, qkv_b, nullptr, nullptr,
                                               Qb, Kb, VT, 8192, 2304, 768);
  attn_kernel<<<768, 256, 0, stream>>>(Qb, Kb, VT, Ob);
  gemm_bt<1><<<dim3(64, 6), 256, 0, stream>>>(Ob, Wout, out_b, x, xout,
                                              nullptr, nullptr, nullptr, 8192, 768, 768);
  ln_kernel<<<8192, 256, 0, stream>>>(xout, ln2_w, ln2_b, Hbuf);
  gemm_bt<2><<<dim3(64, 24), 256, 0, stream>>>(Hbuf, Wff1, ff1_b, nullptr, FFH,
                                               nullptr, nullptr, nullptr, 8192, 3072, 768);
  gemm_bt<3><<<dim3(64, 6), 256, 0, stream>>>(FFH, Wff2, ff2_b, xout, xout,
                                              nullptr, nullptr, nullptr, 8192, 768, 3072);
}

// Round 11
// 314.565 us; speedup vs baseline: 1.1810x; 1.1810x over previous
//
#include <hip/hip_runtime.h>
#include <hip/hip_bf16.h>
#include <cstdint>
#include <cstddef>

#define B_ 4
#define T_ 2048
#define C_ 768
#define H_ 12
#define D_ 64
#define FF_ 3072

typedef __attribute__((ext_vector_type(4))) float f32x4;
typedef __attribute__((ext_vector_type(8))) short s16x8;
typedef __attribute__((ext_vector_type(4))) short s16x4;

static __device__ __forceinline__ short f2bf(float f) {
  union { float fv; unsigned u; } v; v.fv = f;
  unsigned r = v.u + 0x7FFFu + ((v.u >> 16) & 1u);  // RNE
  return (short)(r >> 16);
}

static __device__ __forceinline__ unsigned pkbf2(float a, float b) {
  __hip_bfloat162 h = __float22bfloat162_rn(make_float2(a, b));  // v_cvt_pk_bf16_f32
  union { __hip_bfloat162 h2; unsigned u; } v; v.h2 = h;
  return v.u;
}

// ---------- weight convert+transpose: in[K,N] f32 -> out[N,K] bf16 ----------
__global__ __launch_bounds__(256) void wconv(const float* __restrict__ in,
                                             short* __restrict__ out,
                                             int K, int N) {
  __shared__ float tile[32][33];
  int tk = blockIdx.x * 32, tn = blockIdx.y * 32;
  int lx = threadIdx.x & 31, ly = threadIdx.x >> 5;
#pragma unroll
  for (int i = 0; i < 4; ++i)
    tile[ly + i * 8][lx] = in[(size_t)(tk + ly + i * 8) * N + tn + lx];
  __syncthreads();
#pragma unroll
  for (int i = 0; i < 4; ++i)
    out[(size_t)(tn + ly + i * 8) * K + tk + lx] = f2bf(tile[lx][ly + i * 8]);
}

// ---------- layernorm: x[rows,768] f32 -> bf16 ----------
__global__ __launch_bounds__(256) void ln_kernel(const float* __restrict__ x,
                                                 const float* __restrict__ w,
                                                 const float* __restrict__ b,
                                                 short* __restrict__ out) {
  int row = blockIdx.x, tid = threadIdx.x;
  const float* xr = x + (size_t)row * 768;
  float v0 = xr[tid], v1 = xr[tid + 256], v2 = xr[tid + 512];
  float s = v0 + v1 + v2;
#pragma unroll
  for (int o = 32; o > 0; o >>= 1) s += __shfl_down(s, o);
  __shared__ float r1[4], r2[4];
  if ((tid & 63) == 0) r1[tid >> 6] = s;
  __syncthreads();
  float mean = (r1[0] + r1[1] + r1[2] + r1[3]) * (1.f / 768.f);
  float d0 = v0 - mean, d1 = v1 - mean, d2 = v2 - mean;
  float q = d0 * d0 + d1 * d1 + d2 * d2;
#pragma unroll
  for (int o = 32; o > 0; o >>= 1) q += __shfl_down(q, o);
  if ((tid & 63) == 0) r2[tid >> 6] = q;
  __syncthreads();
  float var = (r2[0] + r2[1] + r2[2] + r2[3]) * (1.f / 768.f);
  float rstd = rsqrtf(var + 1e-5f);
  short* orow = out + (size_t)row * 768;
  orow[tid]       = f2bf(d0 * rstd * w[tid]       + b[tid]);
  orow[tid + 256] = f2bf(d1 * rstd * w[tid + 256] + b[tid + 256]);
  orow[tid + 512] = f2bf(d2 * rstd * w[tid + 512] + b[tid + 512]);
}

// ---------- GEMM: C[M,N] = A[M,K](bf16) * Bt[N,K](bf16)^T + bias, fused epilogues ----------
// BK=64 as two sequential 32-panels: stage both panels (32KB) in one DMA round,
// ONE barrier pair per 64 K (was per 32) -> drain count halved; per-panel read
// pattern identical to the proven BK=32 structure (same banks, same VGPRs).
// MODE 0: qkv scatter (bias, q*=0.125*log2e for exp2-softmax); Q,K -> [B,H,T,D];
//         V -> TRANSPOSED [B,H,D,T]
// MODE 1/3: bias + residual(res f32) -> f32 out
// MODE 2: bias + relu -> bf16 out
template <int MODE>
__global__ __launch_bounds__(256) void gemm_bt(
    const short* __restrict__ A, const short* __restrict__ Bt,
    const float* __restrict__ bias, const float* __restrict__ res,
    void* __restrict__ out,
    short* __restrict__ dq, short* __restrict__ dk, short* __restrict__ dv,
    int M, int N, int K) {
  __shared__ short As[2][128 * 32];
  __shared__ short Bs[2][128 * 32];
  int tid = threadIdx.x;
  int lane = tid & 63;
  int wm = tid >> 7;
  int wn = (tid >> 6) & 1;
  const short* Ab = A + (size_t)blockIdx.x * 128 * K;
  const short* Bb = Bt + (size_t)blockIdx.y * 128 * K;
  f32x4 acc[4][4] = {};
  int i15 = lane & 15, g8 = (lane >> 4) << 3;
  int nk = K >> 6;                    // 64-K steps (two 32-panels each)
  for (int kt = 0; kt < nk; ++kt) {
    int kof = kt << 6;
#pragma unroll
    for (int i = 0; i < 4; ++i) {
      int s = tid + i * 256;          // [0,1024): pan 0 = k 0..31, pan 1 = k 32..63
      int pan = s >> 9, sp = s & 511;
      int row = sp >> 2, kk = ((sp & 3) << 3) + (pan << 5);
      __builtin_amdgcn_global_load_lds(
          (const __attribute__((address_space(1))) unsigned*)(Ab + (size_t)row * K + kof + kk),
          (__attribute__((address_space(3))) unsigned*)(&As[pan][sp * 8]), 16, 0, 0);
      __builtin_amdgcn_global_load_lds(
          (const __attribute__((address_space(1))) unsigned*)(Bb + (size_t)row * K + kof + kk),
          (__attribute__((address_space(3))) unsigned*)(&Bs[pan][sp * 8]), 16, 0, 0);
    }
    __syncthreads();
#pragma unroll
    for (int h = 0; h < 2; ++h) {
      s16x8 af[4], bfr[4];
#pragma unroll
      for (int m = 0; m < 4; ++m)
        af[m] = *(const s16x8*)(&As[h][(wm * 64 + m * 16 + i15) * 32 + g8]);
#pragma unroll
      for (int n = 0; n < 4; ++n)
        bfr[n] = *(const s16x8*)(&Bs[h][(wn * 64 + n * 16 + i15) * 32 + g8]);
#pragma unroll
      for (int m = 0; m < 4; ++m)
#pragma unroll
        for (int n = 0; n < 4; ++n)
          acc[m][n] = __builtin_amdgcn_mfma_f32_16x16x32_bf16(af[m], bfr[n], acc[m][n], 0, 0, 0);
    }
    __syncthreads();
  }
  int row0 = blockIdx.x * 128 + wm * 64;
  int col0 = blockIdx.y * 128 + wn * 64;
  int g4 = (lane >> 4) << 2;
#pragma unroll
  for (int m = 0; m < 4; ++m) {
#pragma unroll
    for (int n = 0; n < 4; ++n) {
      int col = col0 + n * 16 + i15;
      float bv = bias[col];
      float v4[4];
#pragma unroll
      for (int r = 0; r < 4; ++r) v4[r] = acc[m][n][r] + bv;
      int rbase = row0 + m * 16 + g4;
      if constexpr (MODE == 0) {
        int sect = col / 768;            // 0=q 1=k 2=v
        int wi = col - sect * 768;
        int hh = wi >> 6, dd = wi & 63;
        int bb = rbase >> 11, tt = rbase & 2047;
        if (sect == 2) {
          s16x4 o4;
#pragma unroll
          for (int r = 0; r < 4; ++r) o4[r] = f2bf(v4[r]);
          *(s16x4*)(dv + ((size_t)(bb * H_ + hh) * D_ + dd) * T_ + tt) = o4;
        } else {
          short* dst = (sect == 0 ? dq : dk) + ((size_t)(bb * H_ + hh) * T_ + tt) * D_ + dd;
          float sc = sect == 0 ? 0.18033688f : 1.f;   // 0.125 * log2(e)
#pragma unroll
          for (int r = 0; r < 4; ++r) dst[(size_t)r * D_] = f2bf(v4[r] * sc);
        }
      } else if constexpr (MODE == 2) {
#pragma unroll
        for (int r = 0; r < 4; ++r)
          ((short*)out)[(size_t)(rbase + r) * N + col] = f2bf(v4[r] > 0.f ? v4[r] : 0.f);
      } else {
#pragma unroll
        for (int r = 0; r < 4; ++r)
          ((float*)out)[(size_t)(rbase + r) * N + col] = v4[r] + res[(size_t)(rbase + r) * N + col];
      }
    }
  }
}

// ---------- causal flash attention (R7 structure — best measured: 100 us) ----------
// 768 blocks x 2 waves; per head: 32 waves, wave sq handles subtile pair
// (sq, 63-sq) -> each 32-row subtile computed exactly once; nt sum = 65/wave.
// XCD-locality: block i -> XCD i%8 = head%8 (6 heads/XCD, 3MB K+V in L2).
// Softmax in base-2: Q pre-scaled by 0.125*log2e, exp2f = bare v_exp_f32.
// Q/K [B,H,T,D], VT [B,H,D,T] bf16 -> Ob [B,T,C] bf16.
__global__ __launch_bounds__(128) void attn_kernel(const short* __restrict__ Qb,
                                                   const short* __restrict__ Kb,
                                                   const short* __restrict__ VTb,
                                                   short* __restrict__ Ob) {
  int i = blockIdx.x;
  int c = i & 7, j = i >> 3;
  int bx = j & 15, gy = j >> 4;        // bx in [0,16), gy in [0,6)
  int bh = c + (gy << 3);              // head-group; XCD(i)=i%8=c=bh%8
  int bb = bh / H_, hh = bh - bb * H_;
  int tid = threadIdx.x, lane = tid & 63, wv = tid >> 6;
  int sq = (bx << 1) | wv;             // wave's pair index in [0,32)
  const short* Qp = Qb + (size_t)bh * T_ * D_;
  const short* Kp = Kb + (size_t)bh * T_ * D_;
  const short* Vp = VTb + (size_t)bh * D_ * T_;
  int i15 = lane & 15, g = lane >> 4, g8 = g << 3;
  int keyA0 = ((i15 >> 2) << 3) + (i15 & 3);  // perm: A-row i -> key (i/4)*8 + i%4
#pragma unroll 1
  for (int pass = 0; pass < 2; ++pass) {
    int ss = pass ? 63 - sq : sq;
    int wq0 = ss << 5;
    int nt = ss + 1;
    s16x8 qf[2][2];
#pragma unroll
    for (int s = 0; s < 2; ++s) {
      int qrow = wq0 + s * 16 + i15;
      qf[s][0] = *(const s16x8*)(Qp + (size_t)qrow * D_ + g8);
      qf[s][1] = *(const s16x8*)(Qp + (size_t)qrow * D_ + 32 + g8);
    }
    f32x4 oacc[2][4] = {};
    float lsum[2] = {0.f, 0.f};
    // prefetch tile 0
    s16x8 ka0, ka1, kb0, kb1, va0, va1, va2, va3;
    {
      const short* KA = Kp + (size_t)keyA0 * D_;
      ka0 = *(const s16x8*)(KA + g8);
      ka1 = *(const s16x8*)(KA + 32 + g8);
      const short* KB = KA + 4 * D_;
      kb0 = *(const s16x8*)(KB + g8);
      kb1 = *(const s16x8*)(KB + 32 + g8);
      va0 = *(const s16x8*)(Vp + (size_t)(0 * 16 + i15) * T_ + g8);
      va1 = *(const s16x8*)(Vp + (size_t)(1 * 16 + i15) * T_ + g8);
      va2 = *(const s16x8*)(Vp + (size_t)(2 * 16 + i15) * T_ + g8);
      va3 = *(const s16x8*)(Vp + (size_t)(3 * 16 + i15) * T_ + g8);
    }
#pragma unroll 2
    for (int kt = 0; kt < nt; ++kt) {
      int k0 = kt << 5;
      bool last = (kt == nt - 1);
      int kn = last ? 0 : (k0 + 32);   // dummy (L2-hot) prefetch on last trip
      // ---- issue next-tile loads (latency hidden under current compute) ----
      const short* KA = Kp + (size_t)(kn + keyA0) * D_;
      s16x8 nka0 = *(const s16x8*)(KA + g8);
      s16x8 nka1 = *(const s16x8*)(KA + 32 + g8);
      const short* KB = KA + 4 * D_;
      s16x8 nkb0 = *(const s16x8*)(KB + g8);
      s16x8 nkb1 = *(const s16x8*)(KB + 32 + g8);
      s16x8 nva0 = *(const s16x8*)(Vp + (size_t)(0 * 16 + i15) * T_ + kn + g8);
      s16x8 nva1 = *(const s16x8*)(Vp + (size_t)(1 * 16 + i15) * T_ + kn + g8);
      s16x8 nva2 = *(const s16x8*)(Vp + (size_t)(2 * 16 + i15) * T_ + kn + g8);
      s16x8 nva3 = *(const s16x8*)(Vp + (size_t)(3 * 16 + i15) * T_ + kn + g8);
      // ---- compute current tile ----
#pragma unroll
      for (int s = 0; s < 2; ++s) {
        f32x4 sA = {}, sB = {};
        __builtin_amdgcn_s_setprio(1);
        sA = __builtin_amdgcn_mfma_f32_16x16x32_bf16(ka0, qf[s][0], sA, 0, 0, 0);
        sA = __builtin_amdgcn_mfma_f32_16x16x32_bf16(ka1, qf[s][1], sA, 0, 0, 0);
        sB = __builtin_amdgcn_mfma_f32_16x16x32_bf16(kb0, qf[s][0], sB, 0, 0, 0);
        sB = __builtin_amdgcn_mfma_f32_16x16x32_bf16(kb1, qf[s][1], sB, 0, 0, 0);
        __builtin_amdgcn_s_setprio(0);
        int qrow = wq0 + s * 16 + i15;
        int kb = k0 + g8;
        float sa[8];
        if (last) {
#pragma unroll
          for (int r = 0; r < 4; ++r) {
            sa[r]     = (kb + r     <= qrow) ? sA[r] : -1e30f;
            sa[4 + r] = (kb + 4 + r <= qrow) ? sB[r] : -1e30f;
          }
        } else {
#pragma unroll
          for (int r = 0; r < 4; ++r) { sa[r] = sA[r]; sa[4 + r] = sB[r]; }
        }
        float p[8];
        float ps = 0.f;
#pragma unroll
        for (int r = 0; r < 8; ++r) {
          p[r] = exp2f(sa[r]);            // base-2 softmax: bare v_exp_f32
          ps += p[r];
        }
        lsum[s] += ps;                    // lane-local; reduced once after loop
        union { unsigned u[4]; s16x8 v; } pf;
        pf.u[0] = pkbf2(p[0], p[1]);
        pf.u[1] = pkbf2(p[2], p[3]);
        pf.u[2] = pkbf2(p[4], p[5]);
        pf.u[3] = pkbf2(p[6], p[7]);
        __builtin_amdgcn_s_setprio(1);
        oacc[s][0] = __builtin_amdgcn_mfma_f32_16x16x32_bf16(va0, pf.v, oacc[s][0], 0, 0, 0);
        oacc[s][1] = __builtin_amdgcn_mfma_f32_16x16x32_bf16(va1, pf.v, oacc[s][1], 0, 0, 0);
        oacc[s][2] = __builtin_amdgcn_mfma_f32_16x16x32_bf16(va2, pf.v, oacc[s][2], 0, 0, 0);
        oacc[s][3] = __builtin_amdgcn_mfma_f32_16x16x32_bf16(va3, pf.v, oacc[s][3], 0, 0, 0);
        __builtin_amdgcn_s_setprio(0);
      }
      // ---- rotate buffers ----
      ka0 = nka0; ka1 = nka1; kb0 = nkb0; kb1 = nkb1;
      va0 = nva0; va1 = nva1; va2 = nva2; va3 = nva3;
    }
#pragma unroll
    for (int s = 0; s < 2; ++s) {
      float l = lsum[s];
      l += __shfl_xor(l, 16);
      l += __shfl_xor(l, 32);
      float inv = 1.f / l;
      int qrow = wq0 + s * 16 + i15;
      short* op = Ob + ((size_t)(bb * T_ + qrow)) * C_ + hh * D_ + (g << 2);
#pragma unroll
      for (int mt = 0; mt < 4; ++mt) {
        s16x4 o4;
#pragma unroll
        for (int r = 0; r < 4; ++r) o4[r] = f2bf(oacc[s][mt][r] * inv);
        *(s16x4*)(op + mt * 16) = o4;
      }
    }
  }
}

extern "C" void kernel_launch(void* const* d_in, const int* in_sizes, int n_in,
                              void* d_out, int out_size, void* d_ws, size_t ws_size,
                              hipStream_t stream) {
  const float* x     = (const float*)d_in[0];
  const float* ln1_w = (const float*)d_in[1];
  const float* ln1_b = (const float*)d_in[2];
  const float* qkv_w = (const float*)d_in[3];
  const float* qkv_b = (const float*)d_in[4];
  const float* out_w = (const float*)d_in[5];
  const float* out_b = (const float*)d_in[6];
  const float* ln2_w = (const float*)d_in[7];
  const float* ln2_b = (const float*)d_in[8];
  const float* ff1_w = (const float*)d_in[9];
  const float* ff1_b = (const float*)d_in[10];
  const float* ff2_w = (const float*)d_in[11];
  const float* ff2_b = (const float*)d_in[12];

  char* ws = (char*)d_ws;
  short* Wqkv = (short*)(ws + 0);                       // [2304,768]
  short* Wout = (short*)(ws + 3538944);                 // [768,768]
  short* Wff1 = (short*)(ws + 4718592);                 // [3072,768]
  short* Wff2 = (short*)(ws + 9437184);                 // [768,3072]
  short* Hbuf = (short*)(ws + 14155776);                // [8192,768] bf16
  short* Qb   = (short*)(ws + 26738688);                // [B,H,T,D] bf16
  short* Kb   = Qb + 6291456;
  short* VT   = Kb + 6291456;                           // [B,H,D,T] bf16 (V stored transposed)
  short* Ob   = VT + 6291456;                           // [B,T,C] bf16
  short* FFH  = Qb;                                     // alias: [8192,3072] bf16 (Q/K/V/O dead)
  float* xout = (float*)d_out;                          // also x1 residual buffer

  wconv<<<dim3(24, 72), 256, 0, stream>>>(qkv_w, Wqkv, 768, 2304);
  wconv<<<dim3(24, 24), 256, 0, stream>>>(out_w, Wout, 768, 768);
  wconv<<<dim3(24, 96), 256, 0, stream>>>(ff1_w, Wff1, 768, 3072);
  wconv<<<dim3(96, 24), 256, 0, stream>>>(ff2_w, Wff2, 3072, 768);

  ln_kernel<<<8192, 256, 0, stream>>>(x, ln1_w, ln1_b, Hbuf);
  gemm_bt<0><<<dim3(64, 18), 256, 0, stream>>>(Hbuf, Wqkv, qkv_b, nullptr, nullptr,
                                               Qb, Kb, VT, 8192, 2304, 768);
  attn_kernel<<<768, 128, 0, stream>>>(Qb, Kb, VT, Ob);
  gemm_bt<1><<<dim3(64, 6), 256, 0, stream>>>(Ob, Wout, out_b, x, xout,
                                              nullptr, nullptr, nullptr, 8192, 768, 768);
  ln_kernel<<<8192, 256, 0, stream>>>(xout, ln2_w, ln2_b, Hbuf);
  gemm_bt<2><<<dim3(64, 24), 256, 0, stream>>>(Hbuf, Wff1, ff1_b, nullptr, FFH,
                                               nullptr, nullptr, nullptr, 8192, 3072, 768);
  gemm_bt<3><<<dim3(64, 6), 256, 0, stream>>>(FFH, Wff2, ff2_b, xout, xout,
                                              nullptr, nullptr, nullptr, 8192, 768, 3072);
}

// Round 12
// 308.147 us; speedup vs baseline: 1.2055x; 1.0208x over previous
//
#include <hip/hip_runtime.h>
#include <hip/hip_bf16.h>
#include <cstdint>
#include <cstddef>

#define B_ 4
#define T_ 2048
#define C_ 768
#define H_ 12
#define D_ 64
#define FF_ 3072

typedef __attribute__((ext_vector_type(4))) float f32x4;
typedef __attribute__((ext_vector_type(8))) short s16x8;
typedef __attribute__((ext_vector_type(4))) short s16x4;

static __device__ __forceinline__ short f2bf(float f) {
  union { float fv; unsigned u; } v; v.fv = f;
  unsigned r = v.u + 0x7FFFu + ((v.u >> 16) & 1u);  // RNE
  return (short)(r >> 16);
}

static __device__ __forceinline__ unsigned pkbf2(float a, float b) {
  __hip_bfloat162 h = __float22bfloat162_rn(make_float2(a, b));  // v_cvt_pk_bf16_f32
  union { __hip_bfloat162 h2; unsigned u; } v; v.h2 = h;
  return v.u;
}

// ---------- weight convert+transpose: in[K,N] f32 -> out[N,K] bf16 ----------
__global__ __launch_bounds__(256) void wconv(const float* __restrict__ in,
                                             short* __restrict__ out,
                                             int K, int N) {
  __shared__ float tile[32][33];
  int tk = blockIdx.x * 32, tn = blockIdx.y * 32;
  int lx = threadIdx.x & 31, ly = threadIdx.x >> 5;
#pragma unroll
  for (int i = 0; i < 4; ++i)
    tile[ly + i * 8][lx] = in[(size_t)(tk + ly + i * 8) * N + tn + lx];
  __syncthreads();
#pragma unroll
  for (int i = 0; i < 4; ++i)
    out[(size_t)(tn + ly + i * 8) * K + tk + lx] = f2bf(tile[lx][ly + i * 8]);
}

// ---------- layernorm: x[rows,768] f32 -> bf16 ----------
__global__ __launch_bounds__(256) void ln_kernel(const float* __restrict__ x,
                                                 const float* __restrict__ w,
                                                 const float* __restrict__ b,
                                                 short* __restrict__ out) {
  int row = blockIdx.x, tid = threadIdx.x;
  const float* xr = x + (size_t)row * 768;
  float v0 = xr[tid], v1 = xr[tid + 256], v2 = xr[tid + 512];
  float s = v0 + v1 + v2;
#pragma unroll
  for (int o = 32; o > 0; o >>= 1) s += __shfl_down(s, o);
  __shared__ float r1[4], r2[4];
  if ((tid & 63) == 0) r1[tid >> 6] = s;
  __syncthreads();
  float mean = (r1[0] + r1[1] + r1[2] + r1[3]) * (1.f / 768.f);
  float d0 = v0 - mean, d1 = v1 - mean, d2 = v2 - mean;
  float q = d0 * d0 + d1 * d1 + d2 * d2;
#pragma unroll
  for (int o = 32; o > 0; o >>= 1) q += __shfl_down(q, o);
  if ((tid & 63) == 0) r2[tid >> 6] = q;
  __syncthreads();
  float var = (r2[0] + r2[1] + r2[2] + r2[3]) * (1.f / 768.f);
  float rstd = rsqrtf(var + 1e-5f);
  short* orow = out + (size_t)row * 768;
  orow[tid]       = f2bf(d0 * rstd * w[tid]       + b[tid]);
  orow[tid + 256] = f2bf(d1 * rstd * w[tid + 256] + b[tid + 256]);
  orow[tid + 512] = f2bf(d2 * rstd * w[tid + 512] + b[tid + 512]);
}

// ---------- GEMM 128x128, BK=64 two-panel (modes 0,2) ----------
// MODE 0: qkv scatter (bias, q*=0.125*log2e); Q,K -> [B,H,T,D]; V -> [B,H,D,T]
// MODE 2: bias + relu -> bf16 out
template <int MODE>
__global__ __launch_bounds__(256) void gemm_bt(
    const short* __restrict__ A, const short* __restrict__ Bt,
    const float* __restrict__ bias, const float* __restrict__ res,
    void* __restrict__ out,
    short* __restrict__ dq, short* __restrict__ dk, short* __restrict__ dv,
    int M, int N, int K) {
  __shared__ short As[2][128 * 32];
  __shared__ short Bs[2][128 * 32];
  int tid = threadIdx.x;
  int lane = tid & 63;
  int wm = tid >> 7;
  int wn = (tid >> 6) & 1;
  const short* Ab = A + (size_t)blockIdx.x * 128 * K;
  const short* Bb = Bt + (size_t)blockIdx.y * 128 * K;
  f32x4 acc[4][4] = {};
  int i15 = lane & 15, g8 = (lane >> 4) << 3;
  int nk = K >> 6;                    // 64-K steps (two 32-panels each)
  for (int kt = 0; kt < nk; ++kt) {
    int kof = kt << 6;
#pragma unroll
    for (int i = 0; i < 4; ++i) {
      int s = tid + i * 256;          // [0,1024): pan 0 = k 0..31, pan 1 = k 32..63
      int pan = s >> 9, sp = s & 511;
      int row = sp >> 2, kk = ((sp & 3) << 3) + (pan << 5);
      __builtin_amdgcn_global_load_lds(
          (const __attribute__((address_space(1))) unsigned*)(Ab + (size_t)row * K + kof + kk),
          (__attribute__((address_space(3))) unsigned*)(&As[pan][sp * 8]), 16, 0, 0);
      __builtin_amdgcn_global_load_lds(
          (const __attribute__((address_space(1))) unsigned*)(Bb + (size_t)row * K + kof + kk),
          (__attribute__((address_space(3))) unsigned*)(&Bs[pan][sp * 8]), 16, 0, 0);
    }
    __syncthreads();
#pragma unroll
    for (int h = 0; h < 2; ++h) {
      s16x8 af[4], bfr[4];
#pragma unroll
      for (int m = 0; m < 4; ++m)
        af[m] = *(const s16x8*)(&As[h][(wm * 64 + m * 16 + i15) * 32 + g8]);
#pragma unroll
      for (int n = 0; n < 4; ++n)
        bfr[n] = *(const s16x8*)(&Bs[h][(wn * 64 + n * 16 + i15) * 32 + g8]);
#pragma unroll
      for (int m = 0; m < 4; ++m)
#pragma unroll
        for (int n = 0; n < 4; ++n)
          acc[m][n] = __builtin_amdgcn_mfma_f32_16x16x32_bf16(af[m], bfr[n], acc[m][n], 0, 0, 0);
    }
    __syncthreads();
  }
  int row0 = blockIdx.x * 128 + wm * 64;
  int col0 = blockIdx.y * 128 + wn * 64;
  int g4 = (lane >> 4) << 2;
#pragma unroll
  for (int m = 0; m < 4; ++m) {
#pragma unroll
    for (int n = 0; n < 4; ++n) {
      int col = col0 + n * 16 + i15;
      float bv = bias[col];
      float v4[4];
#pragma unroll
      for (int r = 0; r < 4; ++r) v4[r] = acc[m][n][r] + bv;
      int rbase = row0 + m * 16 + g4;
      if constexpr (MODE == 0) {
        int sect = col / 768;            // 0=q 1=k 2=v
        int wi = col - sect * 768;
        int hh = wi >> 6, dd = wi & 63;
        int bb = rbase >> 11, tt = rbase & 2047;
        if (sect == 2) {
          s16x4 o4;
#pragma unroll
          for (int r = 0; r < 4; ++r) o4[r] = f2bf(v4[r]);
          *(s16x4*)(dv + ((size_t)(bb * H_ + hh) * D_ + dd) * T_ + tt) = o4;
        } else {
          short* dst = (sect == 0 ? dq : dk) + ((size_t)(bb * H_ + hh) * T_ + tt) * D_ + dd;
          float sc = sect == 0 ? 0.18033688f : 1.f;   // 0.125 * log2(e)
#pragma unroll
          for (int r = 0; r < 4; ++r) dst[(size_t)r * D_] = f2bf(v4[r] * sc);
        }
      } else {
#pragma unroll
        for (int r = 0; r < 4; ++r)
          ((short*)out)[(size_t)(rbase + r) * N + col] = f2bf(v4[r] > 0.f ? v4[r] : 0.f);
      }
    }
  }
}

// ---------- GEMM 64x128, BK=64, bias+residual -> f32 (out-proj & ff2) ----------
// N=768 GEMMs at 128x128 launch only 384 blocks = 1.5/CU (half the machine's
// block slots idle). BM=64 doubles the grid: 768 blocks = 3/CU, 12 waves/CU
// resident -> inter-block overlap hides the stage+drain serial section.
// 2 waves: wave wn owns cols wn*64..+63, rows 0..63 (A shared).
__global__ __launch_bounds__(128, 3) void gemm64_res(
    const short* __restrict__ A, const short* __restrict__ Bt,
    const float* __restrict__ bias, const float* __restrict__ res,
    float* __restrict__ out, int M, int N, int K) {
  __shared__ short As[2][64 * 32];
  __shared__ short Bs[2][128 * 32];
  int tid = threadIdx.x;
  int lane = tid & 63;
  int wn = tid >> 6;
  const short* Ab = A + (size_t)blockIdx.x * 64 * K;
  const short* Bb = Bt + (size_t)blockIdx.y * 128 * K;
  f32x4 acc[4][4] = {};
  int i15 = lane & 15, g8 = (lane >> 4) << 3;
  int nk = K >> 6;
  for (int kt = 0; kt < nk; ++kt) {
    int kof = kt << 6;
#pragma unroll
    for (int i = 0; i < 4; ++i) {      // A: 64x64 = 512 chunks of 8 elem
      int c = tid + i * 128;
      int pan = c >> 8, sp = c & 255;
      int row = sp >> 2, kk = ((sp & 3) << 3) + (pan << 5);
      __builtin_amdgcn_global_load_lds(
          (const __attribute__((address_space(1))) unsigned*)(Ab + (size_t)row * K + kof + kk),
          (__attribute__((address_space(3))) unsigned*)(&As[pan][sp * 8]), 16, 0, 0);
    }
#pragma unroll
    for (int i = 0; i < 8; ++i) {      // B: 128x64 = 1024 chunks
      int c = tid + i * 128;
      int pan = c >> 9, sp = c & 511;
      int row = sp >> 2, kk = ((sp & 3) << 3) + (pan << 5);
      __builtin_amdgcn_global_load_lds(
          (const __attribute__((address_space(1))) unsigned*)(Bb + (size_t)row * K + kof + kk),
          (__attribute__((address_space(3))) unsigned*)(&Bs[pan][sp * 8]), 16, 0, 0);
    }
    __syncthreads();
#pragma unroll
    for (int h = 0; h < 2; ++h) {
      s16x8 af[4], bfr[4];
#pragma unroll
      for (int m = 0; m < 4; ++m)
        af[m] = *(const s16x8*)(&As[h][(m * 16 + i15) * 32 + g8]);
#pragma unroll
      for (int n = 0; n < 4; ++n)
        bfr[n] = *(const s16x8*)(&Bs[h][(wn * 64 + n * 16 + i15) * 32 + g8]);
#pragma unroll
      for (int m = 0; m < 4; ++m)
#pragma unroll
        for (int n = 0; n < 4; ++n)
          acc[m][n] = __builtin_amdgcn_mfma_f32_16x16x32_bf16(af[m], bfr[n], acc[m][n], 0, 0, 0);
    }
    __syncthreads();
  }
  int row0 = blockIdx.x * 64;
  int col0 = blockIdx.y * 128 + wn * 64;
  int g4 = (lane >> 4) << 2;
#pragma unroll
  for (int m = 0; m < 4; ++m) {
#pragma unroll
    for (int n = 0; n < 4; ++n) {
      int col = col0 + n * 16 + i15;
      float bv = bias[col];
      int rbase = row0 + m * 16 + g4;
#pragma unroll
      for (int r = 0; r < 4; ++r)
        out[(size_t)(rbase + r) * N + col] =
            acc[m][n][r] + bv + res[(size_t)(rbase + r) * N + col];
    }
  }
}

// ---------- causal flash attention (R7 structure — best measured: 100 us) ----------
// 768 blocks x 2 waves; per head: 32 waves, wave sq handles subtile pair
// (sq, 63-sq) -> each 32-row subtile computed exactly once; nt sum = 65/wave.
// XCD-locality: block i -> XCD i%8 = head%8 (6 heads/XCD, 3MB K+V in L2).
// Softmax in base-2: Q pre-scaled by 0.125*log2e, exp2f = bare v_exp_f32.
// Q/K [B,H,T,D], VT [B,H,D,T] bf16 -> Ob [B,T,C] bf16.
__global__ __launch_bounds__(128) void attn_kernel(const short* __restrict__ Qb,
                                                   const short* __restrict__ Kb,
                                                   const short* __restrict__ VTb,
                                                   short* __restrict__ Ob) {
  int i = blockIdx.x;
  int c = i & 7, j = i >> 3;
  int bx = j & 15, gy = j >> 4;        // bx in [0,16), gy in [0,6)
  int bh = c + (gy << 3);              // head-group; XCD(i)=i%8=c=bh%8
  int bb = bh / H_, hh = bh - bb * H_;
  int tid = threadIdx.x, lane = tid & 63, wv = tid >> 6;
  int sq = (bx << 1) | wv;             // wave's pair index in [0,32)
  const short* Qp = Qb + (size_t)bh * T_ * D_;
  const short* Kp = Kb + (size_t)bh * T_ * D_;
  const short* Vp = VTb + (size_t)bh * D_ * T_;
  int i15 = lane & 15, g = lane >> 4, g8 = g << 3;
  int keyA0 = ((i15 >> 2) << 3) + (i15 & 3);  // perm: A-row i -> key (i/4)*8 + i%4
#pragma unroll 1
  for (int pass = 0; pass < 2; ++pass) {
    int ss = pass ? 63 - sq : sq;
    int wq0 = ss << 5;
    int nt = ss + 1;
    s16x8 qf[2][2];
#pragma unroll
    for (int s = 0; s < 2; ++s) {
      int qrow = wq0 + s * 16 + i15;
      qf[s][0] = *(const s16x8*)(Qp + (size_t)qrow * D_ + g8);
      qf[s][1] = *(const s16x8*)(Qp + (size_t)qrow * D_ + 32 + g8);
    }
    f32x4 oacc[2][4] = {};
    float lsum[2] = {0.f, 0.f};
    // prefetch tile 0
    s16x8 ka0, ka1, kb0, kb1, va0, va1, va2, va3;
    {
      const short* KA = Kp + (size_t)keyA0 * D_;
      ka0 = *(const s16x8*)(KA + g8);
      ka1 = *(const s16x8*)(KA + 32 + g8);
      const short* KB = KA + 4 * D_;
      kb0 = *(const s16x8*)(KB + g8);
      kb1 = *(const s16x8*)(KB + 32 + g8);
      va0 = *(const s16x8*)(Vp + (size_t)(0 * 16 + i15) * T_ + g8);
      va1 = *(const s16x8*)(Vp + (size_t)(1 * 16 + i15) * T_ + g8);
      va2 = *(const s16x8*)(Vp + (size_t)(2 * 16 + i15) * T_ + g8);
      va3 = *(const s16x8*)(Vp + (size_t)(3 * 16 + i15) * T_ + g8);
    }
#pragma unroll 2
    for (int kt = 0; kt < nt; ++kt) {
      int k0 = kt << 5;
      bool last = (kt == nt - 1);
      int kn = last ? 0 : (k0 + 32);   // dummy (L2-hot) prefetch on last trip
      // ---- issue next-tile loads (latency hidden under current compute) ----
      const short* KA = Kp + (size_t)(kn + keyA0) * D_;
      s16x8 nka0 = *(const s16x8*)(KA + g8);
      s16x8 nka1 = *(const s16x8*)(KA + 32 + g8);
      const short* KB = KA + 4 * D_;
      s16x8 nkb0 = *(const s16x8*)(KB + g8);
      s16x8 nkb1 = *(const s16x8*)(KB + 32 + g8);
      s16x8 nva0 = *(const s16x8*)(Vp + (size_t)(0 * 16 + i15) * T_ + kn + g8);
      s16x8 nva1 = *(const s16x8*)(Vp + (size_t)(1 * 16 + i15) * T_ + kn + g8);
      s16x8 nva2 = *(const s16x8*)(Vp + (size_t)(2 * 16 + i15) * T_ + kn + g8);
      s16x8 nva3 = *(const s16x8*)(Vp + (size_t)(3 * 16 + i15) * T_ + kn + g8);
      // ---- compute current tile ----
#pragma unroll
      for (int s = 0; s < 2; ++s) {
        f32x4 sA = {}, sB = {};
        __builtin_amdgcn_s_setprio(1);
        sA = __builtin_amdgcn_mfma_f32_16x16x32_bf16(ka0, qf[s][0], sA, 0, 0, 0);
        sA = __builtin_amdgcn_mfma_f32_16x16x32_bf16(ka1, qf[s][1], sA, 0, 0, 0);
        sB = __builtin_amdgcn_mfma_f32_16x16x32_bf16(kb0, qf[s][0], sB, 0, 0, 0);
        sB = __builtin_amdgcn_mfma_f32_16x16x32_bf16(kb1, qf[s][1], sB, 0, 0, 0);
        __builtin_amdgcn_s_setprio(0);
        int qrow = wq0 + s * 16 + i15;
        int kb = k0 + g8;
        float sa[8];
        if (last) {
#pragma unroll
          for (int r = 0; r < 4; ++r) {
            sa[r]     = (kb + r     <= qrow) ? sA[r] : -1e30f;
            sa[4 + r] = (kb + 4 + r <= qrow) ? sB[r] : -1e30f;
          }
        } else {
#pragma unroll
          for (int r = 0; r < 4; ++r) { sa[r] = sA[r]; sa[4 + r] = sB[r]; }
        }
        float p[8];
        float ps = 0.f;
#pragma unroll
        for (int r = 0; r < 8; ++r) {
          p[r] = exp2f(sa[r]);            // base-2 softmax: bare v_exp_f32
          ps += p[r];
        }
        lsum[s] += ps;                    // lane-local; reduced once after loop
        union { unsigned u[4]; s16x8 v; } pf;
        pf.u[0] = pkbf2(p[0], p[1]);
        pf.u[1] = pkbf2(p[2], p[3]);
        pf.u[2] = pkbf2(p[4], p[5]);
        pf.u[3] = pkbf2(p[6], p[7]);
        __builtin_amdgcn_s_setprio(1);
        oacc[s][0] = __builtin_amdgcn_mfma_f32_16x16x32_bf16(va0, pf.v, oacc[s][0], 0, 0, 0);
        oacc[s][1] = __builtin_amdgcn_mfma_f32_16x16x32_bf16(va1, pf.v, oacc[s][1], 0, 0, 0);
        oacc[s][2] = __builtin_amdgcn_mfma_f32_16x16x32_bf16(va2, pf.v, oacc[s][2], 0, 0, 0);
        oacc[s][3] = __builtin_amdgcn_mfma_f32_16x16x32_bf16(va3, pf.v, oacc[s][3], 0, 0, 0);
        __builtin_amdgcn_s_setprio(0);
      }
      // ---- rotate buffers ----
      ka0 = nka0; ka1 = nka1; kb0 = nkb0; kb1 = nkb1;
      va0 = nva0; va1 = nva1; va2 = nva2; va3 = nva3;
    }
#pragma unroll
    for (int s = 0; s < 2; ++s) {
      float l = lsum[s];
      l += __shfl_xor(l, 16);
      l += __shfl_xor(l, 32);
      float inv = 1.f / l;
      int qrow = wq0 + s * 16 + i15;
      short* op = Ob + ((size_t)(bb * T_ + qrow)) * C_ + hh * D_ + (g << 2);
#pragma unroll
      for (int mt = 0; mt < 4; ++mt) {
        s16x4 o4;
#pragma unroll
        for (int r = 0; r < 4; ++r) o4[r] = f2bf(oacc[s][mt][r] * inv);
        *(s16x4*)(op + mt * 16) = o4;
      }
    }
  }
}

extern "C" void kernel_launch(void* const* d_in, const int* in_sizes, int n_in,
                              void* d_out, int out_size, void* d_ws, size_t ws_size,
                              hipStream_t stream) {
  const float* x     = (const float*)d_in[0];
  const float* ln1_w = (const float*)d_in[1];
  const float* ln1_b = (const float*)d_in[2];
  const float* qkv_w = (const float*)d_in[3];
  const float* qkv_b = (const float*)d_in[4];
  const float* out_w = (const float*)d_in[5];
  const float* out_b = (const float*)d_in[6];
  const float* ln2_w = (const float*)d_in[7];
  const float* ln2_b = (const float*)d_in[8];
  const float* ff1_w = (const float*)d_in[9];
  const float* ff1_b = (const float*)d_in[10];
  const float* ff2_w = (const float*)d_in[11];
  const float* ff2_b = (const float*)d_in[12];

  char* ws = (char*)d_ws;
  short* Wqkv = (short*)(ws + 0);                       // [2304,768]
  short* Wout = (short*)(ws + 3538944);                 // [768,768]
  short* Wff1 = (short*)(ws + 4718592);                 // [3072,768]
  short* Wff2 = (short*)(ws + 9437184);                 // [768,3072]
  short* Hbuf = (short*)(ws + 14155776);                // [8192,768] bf16
  short* Qb   = (short*)(ws + 26738688);                // [B,H,T,D] bf16
  short* Kb   = Qb + 6291456;
  short* VT   = Kb + 6291456;                           // [B,H,D,T] bf16 (V stored transposed)
  short* Ob   = VT + 6291456;                           // [B,T,C] bf16
  short* FFH  = Qb;                                     // alias: [8192,3072] bf16 (Q/K/V/O dead)
  float* xout = (float*)d_out;                          // also x1 residual buffer

  wconv<<<dim3(24, 72), 256, 0, stream>>>(qkv_w, Wqkv, 768, 2304);
  wconv<<<dim3(24, 24), 256, 0, stream>>>(out_w, Wout, 768, 768);
  wconv<<<dim3(24, 96), 256, 0, stream>>>(ff1_w, Wff1, 768, 3072);
  wconv<<<dim3(96, 24), 256, 0, stream>>>(ff2_w, Wff2, 3072, 768);

  ln_kernel<<<8192, 256, 0, stream>>>(x, ln1_w, ln1_b, Hbuf);
  gemm_bt<0><<<dim3(64, 18), 256, 0, stream>>>(Hbuf, Wqkv, qkv_b, nullptr, nullptr,
                                               Qb, Kb, VT, 8192, 2304, 768);
  attn_kernel<<<768, 128, 0, stream>>>(Qb, Kb, VT, Ob);
  gemm64_res<<<dim3(128, 6), 128, 0, stream>>>(Ob, Wout, out_b, x, xout, 8192, 768, 768);
  ln_kernel<<<8192, 256, 0, stream>>>(xout, ln2_w, ln2_b, Hbuf);
  gemm_bt<2><<<dim3(64, 24), 256, 0, stream>>>(Hbuf, Wff1, ff1_b, nullptr, FFH,
                                               nullptr, nullptr, nullptr, 8192, 3072, 768);
  gemm64_res<<<dim3(128, 6), 128, 0, stream>>>(FFH, Wff2, ff2_b, xout, xout, 8192, 768, 3072);
}

// Round 13
// 288.448 us; speedup vs baseline: 1.2879x; 1.0683x over previous
//
#include <hip/hip_runtime.h>
#include <hip/hip_bf16.h>
#include <cstdint>
#include <cstddef>

#define B_ 4
#define T_ 2048
#define C_ 768
#define H_ 12
#define D_ 64
#define FF_ 3072

typedef __attribute__((ext_vector_type(4))) float f32x4;
typedef __attribute__((ext_vector_type(8))) short s16x8;
typedef __attribute__((ext_vector_type(4))) short s16x4;

static __device__ __forceinline__ short f2bf(float f) {
  union { float fv; unsigned u; } v; v.fv = f;
  unsigned r = v.u + 0x7FFFu + ((v.u >> 16) & 1u);  // RNE
  return (short)(r >> 16);
}

static __device__ __forceinline__ unsigned pkbf2(float a, float b) {
  __hip_bfloat162 h = __float22bfloat162_rn(make_float2(a, b));  // v_cvt_pk_bf16_f32
  union { __hip_bfloat162 h2; unsigned u; } v; v.h2 = h;
  return v.u;
}

// ---------- weight convert+transpose: in[K,N] f32 -> out[N,K] bf16 ----------
__global__ __launch_bounds__(256) void wconv(const float* __restrict__ in,
                                             short* __restrict__ out,
                                             int K, int N) {
  __shared__ float tile[32][33];
  int tk = blockIdx.x * 32, tn = blockIdx.y * 32;
  int lx = threadIdx.x & 31, ly = threadIdx.x >> 5;
#pragma unroll
  for (int i = 0; i < 4; ++i)
    tile[ly + i * 8][lx] = in[(size_t)(tk + ly + i * 8) * N + tn + lx];
  __syncthreads();
#pragma unroll
  for (int i = 0; i < 4; ++i)
    out[(size_t)(tn + ly + i * 8) * K + tk + lx] = f2bf(tile[lx][ly + i * 8]);
}

// ---------- layernorm: x[rows,768] f32 -> bf16 ----------
__global__ __launch_bounds__(256) void ln_kernel(const float* __restrict__ x,
                                                 const float* __restrict__ w,
                                                 const float* __restrict__ b,
                                                 short* __restrict__ out) {
  int row = blockIdx.x, tid = threadIdx.x;
  const float* xr = x + (size_t)row * 768;
  float v0 = xr[tid], v1 = xr[tid + 256], v2 = xr[tid + 512];
  float s = v0 + v1 + v2;
#pragma unroll
  for (int o = 32; o > 0; o >>= 1) s += __shfl_down(s, o);
  __shared__ float r1[4], r2[4];
  if ((tid & 63) == 0) r1[tid >> 6] = s;
  __syncthreads();
  float mean = (r1[0] + r1[1] + r1[2] + r1[3]) * (1.f / 768.f);
  float d0 = v0 - mean, d1 = v1 - mean, d2 = v2 - mean;
  float q = d0 * d0 + d1 * d1 + d2 * d2;
#pragma unroll
  for (int o = 32; o > 0; o >>= 1) q += __shfl_down(q, o);
  if ((tid & 63) == 0) r2[tid >> 6] = q;
  __syncthreads();
  float var = (r2[0] + r2[1] + r2[2] + r2[3]) * (1.f / 768.f);
  float rstd = rsqrtf(var + 1e-5f);
  short* orow = out + (size_t)row * 768;
  orow[tid]       = f2bf(d0 * rstd * w[tid]       + b[tid]);
  orow[tid + 256] = f2bf(d1 * rstd * w[tid + 256] + b[tid + 256]);
  orow[tid + 512] = f2bf(d2 * rstd * w[tid + 512] + b[tid + 512]);
}

// ---------- GEMM 128x128, BK=64 two-panel (modes 0,2) ----------
template <int MODE>
__global__ __launch_bounds__(256) void gemm_bt(
    const short* __restrict__ A, const short* __restrict__ Bt,
    const float* __restrict__ bias, const float* __restrict__ res,
    void* __restrict__ out,
    short* __restrict__ dq, short* __restrict__ dk, short* __restrict__ dv,
    int M, int N, int K) {
  __shared__ short As[2][128 * 32];
  __shared__ short Bs[2][128 * 32];
  int tid = threadIdx.x;
  int lane = tid & 63;
  int wm = tid >> 7;
  int wn = (tid >> 6) & 1;
  const short* Ab = A + (size_t)blockIdx.x * 128 * K;
  const short* Bb = Bt + (size_t)blockIdx.y * 128 * K;
  f32x4 acc[4][4] = {};
  int i15 = lane & 15, g8 = (lane >> 4) << 3;
  int nk = K >> 6;
  for (int kt = 0; kt < nk; ++kt) {
    int kof = kt << 6;
#pragma unroll
    for (int i = 0; i < 4; ++i) {
      int s = tid + i * 256;
      int pan = s >> 9, sp = s & 511;
      int row = sp >> 2, kk = ((sp & 3) << 3) + (pan << 5);
      __builtin_amdgcn_global_load_lds(
          (const __attribute__((address_space(1))) unsigned*)(Ab + (size_t)row * K + kof + kk),
          (__attribute__((address_space(3))) unsigned*)(&As[pan][sp * 8]), 16, 0, 0);
      __builtin_amdgcn_global_load_lds(
          (const __attribute__((address_space(1))) unsigned*)(Bb + (size_t)row * K + kof + kk),
          (__attribute__((address_space(3))) unsigned*)(&Bs[pan][sp * 8]), 16, 0, 0);
    }
    __syncthreads();
#pragma unroll
    for (int h = 0; h < 2; ++h) {
      s16x8 af[4], bfr[4];
#pragma unroll
      for (int m = 0; m < 4; ++m)
        af[m] = *(const s16x8*)(&As[h][(wm * 64 + m * 16 + i15) * 32 + g8]);
#pragma unroll
      for (int n = 0; n < 4; ++n)
        bfr[n] = *(const s16x8*)(&Bs[h][(wn * 64 + n * 16 + i15) * 32 + g8]);
#pragma unroll
      for (int m = 0; m < 4; ++m)
#pragma unroll
        for (int n = 0; n < 4; ++n)
          acc[m][n] = __builtin_amdgcn_mfma_f32_16x16x32_bf16(af[m], bfr[n], acc[m][n], 0, 0, 0);
    }
    __syncthreads();
  }
  int row0 = blockIdx.x * 128 + wm * 64;
  int col0 = blockIdx.y * 128 + wn * 64;
  int g4 = (lane >> 4) << 2;
#pragma unroll
  for (int m = 0; m < 4; ++m) {
#pragma unroll
    for (int n = 0; n < 4; ++n) {
      int col = col0 + n * 16 + i15;
      float bv = bias[col];
      float v4[4];
#pragma unroll
      for (int r = 0; r < 4; ++r) v4[r] = acc[m][n][r] + bv;
      int rbase = row0 + m * 16 + g4;
      if constexpr (MODE == 0) {
        int sect = col / 768;            // 0=q 1=k 2=v
        int wi = col - sect * 768;
        int hh = wi >> 6, dd = wi & 63;
        int bb = rbase >> 11, tt = rbase & 2047;
        if (sect == 2) {
          s16x4 o4;
#pragma unroll
          for (int r = 0; r < 4; ++r) o4[r] = f2bf(v4[r]);
          *(s16x4*)(dv + ((size_t)(bb * H_ + hh) * D_ + dd) * T_ + tt) = o4;
        } else {
          short* dst = (sect == 0 ? dq : dk) + ((size_t)(bb * H_ + hh) * T_ + tt) * D_ + dd;
          float sc = sect == 0 ? 0.18033688f : 1.f;   // 0.125 * log2(e)
#pragma unroll
          for (int r = 0; r < 4; ++r) dst[(size_t)r * D_] = f2bf(v4[r] * sc);
        }
      } else {
#pragma unroll
        for (int r = 0; r < 4; ++r)
          ((short*)out)[(size_t)(rbase + r) * N + col] = f2bf(v4[r] > 0.f ? v4[r] : 0.f);
      }
    }
  }
}

// ---------- GEMM 64x128, BK=64, bias+residual -> f32 (out-proj & ff2) ----------
__global__ __launch_bounds__(128, 3) void gemm64_res(
    const short* __restrict__ A, const short* __restrict__ Bt,
    const float* __restrict__ bias, const float* __restrict__ res,
    float* __restrict__ out, int M, int N, int K) {
  __shared__ short As[2][64 * 32];
  __shared__ short Bs[2][128 * 32];
  int tid = threadIdx.x;
  int lane = tid & 63;
  int wn = tid >> 6;
  const short* Ab = A + (size_t)blockIdx.x * 64 * K;
  const short* Bb = Bt + (size_t)blockIdx.y * 128 * K;
  f32x4 acc[4][4] = {};
  int i15 = lane & 15, g8 = (lane >> 4) << 3;
  int nk = K >> 6;
  for (int kt = 0; kt < nk; ++kt) {
    int kof = kt << 6;
#pragma unroll
    for (int i = 0; i < 4; ++i) {
      int c = tid + i * 128;
      int pan = c >> 8, sp = c & 255;
      int row = sp >> 2, kk = ((sp & 3) << 3) + (pan << 5);
      __builtin_amdgcn_global_load_lds(
          (const __attribute__((address_space(1))) unsigned*)(Ab + (size_t)row * K + kof + kk),
          (__attribute__((address_space(3))) unsigned*)(&As[pan][sp * 8]), 16, 0, 0);
    }
#pragma unroll
    for (int i = 0; i < 8; ++i) {
      int c = tid + i * 128;
      int pan = c >> 9, sp = c & 511;
      int row = sp >> 2, kk = ((sp & 3) << 3) + (pan << 5);
      __builtin_amdgcn_global_load_lds(
          (const __attribute__((address_space(1))) unsigned*)(Bb + (size_t)row * K + kof + kk),
          (__attribute__((address_space(3))) unsigned*)(&Bs[pan][sp * 8]), 16, 0, 0);
    }
    __syncthreads();
#pragma unroll
    for (int h = 0; h < 2; ++h) {
      s16x8 af[4], bfr[4];
#pragma unroll
      for (int m = 0; m < 4; ++m)
        af[m] = *(const s16x8*)(&As[h][(m * 16 + i15) * 32 + g8]);
#pragma unroll
      for (int n = 0; n < 4; ++n)
        bfr[n] = *(const s16x8*)(&Bs[h][(wn * 64 + n * 16 + i15) * 32 + g8]);
#pragma unroll
      for (int m = 0; m < 4; ++m)
#pragma unroll
        for (int n = 0; n < 4; ++n)
          acc[m][n] = __builtin_amdgcn_mfma_f32_16x16x32_bf16(af[m], bfr[n], acc[m][n], 0, 0, 0);
    }
    __syncthreads();
  }
  int row0 = blockIdx.x * 64;
  int col0 = blockIdx.y * 128 + wn * 64;
  int g4 = (lane >> 4) << 2;
#pragma unroll
  for (int m = 0; m < 4; ++m) {
#pragma unroll
    for (int n = 0; n < 4; ++n) {
      int col = col0 + n * 16 + i15;
      float bv = bias[col];
      int rbase = row0 + m * 16 + g4;
#pragma unroll
      for (int r = 0; r < 4; ++r)
        out[(size_t)(rbase + r) * N + col] =
            acc[m][n][r] + bv + res[(size_t)(rbase + r) * N + col];
    }
  }
}

// ---------- causal flash attention: LDS-DMA staged, all-waves-compute ----------
// 1536 blocks x 4 waves. Block = 64 q-rows; wave owns 16 rows. 64-key K/V
// tiles staged once/block via global_load_lds (contiguous DMA: TA transactions
// cut ~4x vs per-wave scattered loads = the ~650cyc/trip pin of R2-R9).
// Double-buffered, ONE barrier/tile. No split-K, no combine (R10's parity
// idling removed). Swizzle f(r)=(r&7)^((r&8)>>1): injective on perm'd K rows
// AND consecutive V rows (R10's f was not -> 3.2M conflicts); linear DMA dest
// + inverse-swz source + swz read (rule #21). Diagonal tile: wave-uniform
// skip of the fully-masked key group. XCD: block i -> XCD i%8 = head%8.
// Q/K [B,H,T,D] (Q pre-scaled 0.125*log2e), VT [B,H,D,T] bf16 -> Ob [B,T,C].
__global__ __launch_bounds__(256) void attn_kernel(const short* __restrict__ Qb,
                                                   const short* __restrict__ Kb,
                                                   const short* __restrict__ VTb,
                                                   short* __restrict__ Ob) {
  __shared__ short Ks[2][4096];   // [64 keys][8 chunks x 8 shorts] swizzled
  __shared__ short Vs[2][4096];   // [64 d][8 chunks x 8 shorts] swizzled
  int i = blockIdx.x;
  int c = i & 7, j = i >> 3;
  int qb = 31 - (j & 31);              // longest blocks first
  int gy = j >> 5;                     // head-group [0,6)
  int bh = c + (gy << 3);              // XCD(i)=i%8=c=bh%8
  int bb = bh / H_, hh = bh - bb * H_;
  int tid = threadIdx.x, lane = tid & 63, wv = tid >> 6;
  int q0 = qb << 6;
  int nt = qb + 1;
  const short* Qp = Qb + (size_t)bh * T_ * D_;
  const short* Kp = Kb + (size_t)bh * T_ * D_;
  const short* Vp = VTb + (size_t)bh * D_ * T_;
  int i15 = lane & 15, g = lane >> 4, g8 = g << 3;
  int keyA0 = ((i15 >> 2) << 3) + (i15 & 3);  // perm: A-row i -> key (i/4)*8+i%4
  int keyB0 = keyA0 + 4;
  int fA = (keyA0 & 7) ^ ((keyA0 & 8) >> 1);
  int fB = (keyB0 & 7) ^ ((keyB0 & 8) >> 1);
  int fV = (i15 & 7) ^ ((i15 & 8) >> 1);
  // K read offsets (shorts): row*64 + ((chunk^f)<<3), chunk = h*4+g
  int oA[2], oB[2], oV[2];
#pragma unroll
  for (int h = 0; h < 2; ++h) {
    oA[h] = keyA0 * 64 + (((h * 4 + g) ^ fA) << 3);
    oB[h] = keyB0 * 64 + (((h * 4 + g) ^ fB) << 3);
    oV[h] = i15 * 64 + (((h * 4 + g) ^ fV) << 3);   // h = ks here
  }
  int qrow = q0 + wv * 16 + i15;
  s16x8 qf0 = *(const s16x8*)(Qp + (size_t)qrow * D_ + g8);
  s16x8 qf1 = *(const s16x8*)(Qp + (size_t)qrow * D_ + 32 + g8);
  f32x4 oacc[4] = {};
  float lsum = 0.f;

  auto stage = [&](int buf, int t) {
    int k0 = t << 6;
#pragma unroll
    for (int qq = 0; qq < 2; ++qq) {
      int m = tid + qq * 256;
      int r = m >> 3, cd = m & 7;
      int cs = cd ^ ((r & 7) ^ ((r & 8) >> 1));   // inverse swizzle on SOURCE
      __builtin_amdgcn_global_load_lds(
          (const __attribute__((address_space(1))) unsigned*)(Kp + (size_t)(k0 + r) * D_ + (cs << 3)),
          (__attribute__((address_space(3))) unsigned*)(&Ks[buf][m * 8]), 16, 0, 0);
      __builtin_amdgcn_global_load_lds(
          (const __attribute__((address_space(1))) unsigned*)(Vp + (size_t)r * T_ + k0 + (cs << 3)),
          (__attribute__((address_space(3))) unsigned*)(&Vs[buf][m * 8]), 16, 0, 0);
    }
  };

  stage(0, 0);
  __syncthreads();
  int cur = 0;
#pragma unroll 1
  for (int t = 0; t < nt; ++t) {
    if (t + 1 < nt) stage(cur ^ 1, t + 1);
    const short* KB = &Ks[cur][0];
    const short* VB = &Vs[cur][0];
    bool diag = (t == nt - 1);
    int k0 = t << 6;
#pragma unroll
    for (int ks = 0; ks < 2; ++ks) {
      if (!(ks == 1 && diag && wv < 2)) {        // skip fully-masked group
        s16x8 ka0 = *(const s16x8*)(KB + (ks << 11) + oA[0]);
        s16x8 ka1 = *(const s16x8*)(KB + (ks << 11) + oA[1]);
        s16x8 kb0 = *(const s16x8*)(KB + (ks << 11) + oB[0]);
        s16x8 kb1 = *(const s16x8*)(KB + (ks << 11) + oB[1]);
        f32x4 sA = {}, sB = {};
        __builtin_amdgcn_s_setprio(1);
        sA = __builtin_amdgcn_mfma_f32_16x16x32_bf16(ka0, qf0, sA, 0, 0, 0);
        sA = __builtin_amdgcn_mfma_f32_16x16x32_bf16(ka1, qf1, sA, 0, 0, 0);
        sB = __builtin_amdgcn_mfma_f32_16x16x32_bf16(kb0, qf0, sB, 0, 0, 0);
        sB = __builtin_amdgcn_mfma_f32_16x16x32_bf16(kb1, qf1, sB, 0, 0, 0);
        __builtin_amdgcn_s_setprio(0);
        int kb = k0 + (ks << 5) + g8;
        float sa[8];
        bool needmask = diag && ((wv < 2) == (ks == 0));
        if (needmask) {
#pragma unroll
          for (int r = 0; r < 4; ++r) {
            sa[r]     = (kb + r     <= qrow) ? sA[r] : -1e30f;
            sa[4 + r] = (kb + 4 + r <= qrow) ? sB[r] : -1e30f;
          }
        } else {
#pragma unroll
          for (int r = 0; r < 4; ++r) { sa[r] = sA[r]; sa[4 + r] = sB[r]; }
        }
        float p[8];
        float ps = 0.f;
#pragma unroll
        for (int r = 0; r < 8; ++r) {
          p[r] = exp2f(sa[r]);
          ps += p[r];
        }
        lsum += ps;
        union { unsigned u[4]; s16x8 v; } pf;
        pf.u[0] = pkbf2(p[0], p[1]);
        pf.u[1] = pkbf2(p[2], p[3]);
        pf.u[2] = pkbf2(p[4], p[5]);
        pf.u[3] = pkbf2(p[6], p[7]);
        s16x8 vf0 = *(const s16x8*)(VB + 0    + oV[ks]);
        s16x8 vf1 = *(const s16x8*)(VB + 1024 + oV[ks]);
        s16x8 vf2 = *(const s16x8*)(VB + 2048 + oV[ks]);
        s16x8 vf3 = *(const s16x8*)(VB + 3072 + oV[ks]);
        __builtin_amdgcn_s_setprio(1);
        oacc[0] = __builtin_amdgcn_mfma_f32_16x16x32_bf16(vf0, pf.v, oacc[0], 0, 0, 0);
        oacc[1] = __builtin_amdgcn_mfma_f32_16x16x32_bf16(vf1, pf.v, oacc[1], 0, 0, 0);
        oacc[2] = __builtin_amdgcn_mfma_f32_16x16x32_bf16(vf2, pf.v, oacc[2], 0, 0, 0);
        oacc[3] = __builtin_amdgcn_mfma_f32_16x16x32_bf16(vf3, pf.v, oacc[3], 0, 0, 0);
        __builtin_amdgcn_s_setprio(0);
      }
    }
    __syncthreads();
    cur ^= 1;
  }
  float l = lsum;
  l += __shfl_xor(l, 16);
  l += __shfl_xor(l, 32);
  float inv = 1.f / l;
  short* op = Ob + ((size_t)(bb * T_ + qrow)) * C_ + hh * D_ + (g << 2);
#pragma unroll
  for (int mt = 0; mt < 4; ++mt) {
    s16x4 o4;
#pragma unroll
    for (int r = 0; r < 4; ++r) o4[r] = f2bf(oacc[mt][r] * inv);
    *(s16x4*)(op + mt * 16) = o4;
  }
}

extern "C" void kernel_launch(void* const* d_in, const int* in_sizes, int n_in,
                              void* d_out, int out_size, void* d_ws, size_t ws_size,
                              hipStream_t stream) {
  const float* x     = (const float*)d_in[0];
  const float* ln1_w = (const float*)d_in[1];
  const float* ln1_b = (const float*)d_in[2];
  const float* qkv_w = (const float*)d_in[3];
  const float* qkv_b = (const float*)d_in[4];
  const float* out_w = (const float*)d_in[5];
  const float* out_b = (const float*)d_in[6];
  const float* ln2_w = (const float*)d_in[7];
  const float* ln2_b = (const float*)d_in[8];
  const float* ff1_w = (const float*)d_in[9];
  const float* ff1_b = (const float*)d_in[10];
  const float* ff2_w = (const float*)d_in[11];
  const float* ff2_b = (const float*)d_in[12];

  char* ws = (char*)d_ws;
  short* Wqkv = (short*)(ws + 0);                       // [2304,768]
  short* Wout = (short*)(ws + 3538944);                 // [768,768]
  short* Wff1 = (short*)(ws + 4718592);                 // [3072,768]
  short* Wff2 = (short*)(ws + 9437184);                 // [768,3072]
  short* Hbuf = (short*)(ws + 14155776);                // [8192,768] bf16
  short* Qb   = (short*)(ws + 26738688);                // [B,H,T,D] bf16
  short* Kb   = Qb + 6291456;
  short* VT   = Kb + 6291456;                           // [B,H,D,T] bf16 (V stored transposed)
  short* Ob   = VT + 6291456;                           // [B,T,C] bf16
  short* FFH  = Qb;                                     // alias: [8192,3072] bf16 (Q/K/V/O dead)
  float* xout = (float*)d_out;                          // also x1 residual buffer

  wconv<<<dim3(24, 72), 256, 0, stream>>>(qkv_w, Wqkv, 768, 2304);
  wconv<<<dim3(24, 24), 256, 0, stream>>>(out_w, Wout, 768, 768);
  wconv<<<dim3(24, 96), 256, 0, stream>>>(ff1_w, Wff1, 768, 3072);
  wconv<<<dim3(96, 24), 256, 0, stream>>>(ff2_w, Wff2, 3072, 768);

  ln_kernel<<<8192, 256, 0, stream>>>(x, ln1_w, ln1_b, Hbuf);
  gemm_bt<0><<<dim3(64, 18), 256, 0, stream>>>(Hbuf, Wqkv, qkv_b, nullptr, nullptr,
                                               Qb, Kb, VT, 8192, 2304, 768);
  attn_kernel<<<1536, 256, 0, stream>>>(Qb, Kb, VT, Ob);
  gemm64_res<<<dim3(128, 6), 128, 0, stream>>>(Ob, Wout, out_b, x, xout, 8192, 768, 768);
  ln_kernel<<<8192, 256, 0, stream>>>(xout, ln2_w, ln2_b, Hbuf);
  gemm_bt<2><<<dim3(64, 24), 256, 0, stream>>>(Hbuf, Wff1, ff1_b, nullptr, FFH,
                                               nullptr, nullptr, nullptr, 8192, 3072, 768);
  gemm64_res<<<dim3(128, 6), 128, 0, stream>>>(FFH, Wff2, ff2_b, xout, xout, 8192, 768, 3072);
}

// Round 14
// 280.410 us; speedup vs baseline: 1.3248x; 1.0287x over previous
//
#include <hip/hip_runtime.h>
#include <hip/hip_bf16.h>
#include <cstdint>
#include <cstddef>

#define B_ 4
#define T_ 2048
#define C_ 768
#define H_ 12
#define D_ 64
#define FF_ 3072

typedef __attribute__((ext_vector_type(4))) float f32x4;
typedef __attribute__((ext_vector_type(8))) short s16x8;
typedef __attribute__((ext_vector_type(4))) short s16x4;

static __device__ __forceinline__ short f2bf(float f) {
  union { float fv; unsigned u; } v; v.fv = f;
  unsigned r = v.u + 0x7FFFu + ((v.u >> 16) & 1u);  // RNE
  return (short)(r >> 16);
}

static __device__ __forceinline__ unsigned pkbf2(float a, float b) {
  __hip_bfloat162 h = __float22bfloat162_rn(make_float2(a, b));  // v_cvt_pk_bf16_f32
  union { __hip_bfloat162 h2; unsigned u; } v; v.h2 = h;
  return v.u;
}

// ---------- weight convert+transpose: in[K,N] f32 -> out[N,K] bf16 ----------
__global__ __launch_bounds__(256) void wconv(const float* __restrict__ in,
                                             short* __restrict__ out,
                                             int K, int N) {
  __shared__ float tile[32][33];
  int tk = blockIdx.x * 32, tn = blockIdx.y * 32;
  int lx = threadIdx.x & 31, ly = threadIdx.x >> 5;
#pragma unroll
  for (int i = 0; i < 4; ++i)
    tile[ly + i * 8][lx] = in[(size_t)(tk + ly + i * 8) * N + tn + lx];
  __syncthreads();
#pragma unroll
  for (int i = 0; i < 4; ++i)
    out[(size_t)(tn + ly + i * 8) * K + tk + lx] = f2bf(tile[lx][ly + i * 8]);
}

// ---------- layernorm: x[rows,768] f32 -> bf16 ----------
__global__ __launch_bounds__(256) void ln_kernel(const float* __restrict__ x,
                                                 const float* __restrict__ w,
                                                 const float* __restrict__ b,
                                                 short* __restrict__ out) {
  int row = blockIdx.x, tid = threadIdx.x;
  const float* xr = x + (size_t)row * 768;
  float v0 = xr[tid], v1 = xr[tid + 256], v2 = xr[tid + 512];
  float s = v0 + v1 + v2;
#pragma unroll
  for (int o = 32; o > 0; o >>= 1) s += __shfl_down(s, o);
  __shared__ float r1[4], r2[4];
  if ((tid & 63) == 0) r1[tid >> 6] = s;
  __syncthreads();
  float mean = (r1[0] + r1[1] + r1[2] + r1[3]) * (1.f / 768.f);
  float d0 = v0 - mean, d1 = v1 - mean, d2 = v2 - mean;
  float q = d0 * d0 + d1 * d1 + d2 * d2;
#pragma unroll
  for (int o = 32; o > 0; o >>= 1) q += __shfl_down(q, o);
  if ((tid & 63) == 0) r2[tid >> 6] = q;
  __syncthreads();
  float var = (r2[0] + r2[1] + r2[2] + r2[3]) * (1.f / 768.f);
  float rstd = rsqrtf(var + 1e-5f);
  short* orow = out + (size_t)row * 768;
  orow[tid]       = f2bf(d0 * rstd * w[tid]       + b[tid]);
  orow[tid + 256] = f2bf(d1 * rstd * w[tid + 256] + b[tid + 256]);
  orow[tid + 512] = f2bf(d2 * rstd * w[tid + 512] + b[tid + 512]);
}

// ---------- GEMM 128x128, BK=64 two-panel (modes 0,2) ----------
template <int MODE>
__global__ __launch_bounds__(256) void gemm_bt(
    const short* __restrict__ A, const short* __restrict__ Bt,
    const float* __restrict__ bias, const float* __restrict__ res,
    void* __restrict__ out,
    short* __restrict__ dq, short* __restrict__ dk, short* __restrict__ dv,
    int M, int N, int K) {
  __shared__ short As[2][128 * 32];
  __shared__ short Bs[2][128 * 32];
  int tid = threadIdx.x;
  int lane = tid & 63;
  int wm = tid >> 7;
  int wn = (tid >> 6) & 1;
  const short* Ab = A + (size_t)blockIdx.x * 128 * K;
  const short* Bb = Bt + (size_t)blockIdx.y * 128 * K;
  f32x4 acc[4][4] = {};
  int i15 = lane & 15, g8 = (lane >> 4) << 3;
  int nk = K >> 6;
  for (int kt = 0; kt < nk; ++kt) {
    int kof = kt << 6;
#pragma unroll
    for (int i = 0; i < 4; ++i) {
      int s = tid + i * 256;
      int pan = s >> 9, sp = s & 511;
      int row = sp >> 2, kk = ((sp & 3) << 3) + (pan << 5);
      __builtin_amdgcn_global_load_lds(
          (const __attribute__((address_space(1))) unsigned*)(Ab + (size_t)row * K + kof + kk),
          (__attribute__((address_space(3))) unsigned*)(&As[pan][sp * 8]), 16, 0, 0);
      __builtin_amdgcn_global_load_lds(
          (const __attribute__((address_space(1))) unsigned*)(Bb + (size_t)row * K + kof + kk),
          (__attribute__((address_space(3))) unsigned*)(&Bs[pan][sp * 8]), 16, 0, 0);
    }
    __syncthreads();
#pragma unroll
    for (int h = 0; h < 2; ++h) {
      s16x8 af[4], bfr[4];
#pragma unroll
      for (int m = 0; m < 4; ++m)
        af[m] = *(const s16x8*)(&As[h][(wm * 64 + m * 16 + i15) * 32 + g8]);
#pragma unroll
      for (int n = 0; n < 4; ++n)
        bfr[n] = *(const s16x8*)(&Bs[h][(wn * 64 + n * 16 + i15) * 32 + g8]);
#pragma unroll
      for (int m = 0; m < 4; ++m)
#pragma unroll
        for (int n = 0; n < 4; ++n)
          acc[m][n] = __builtin_amdgcn_mfma_f32_16x16x32_bf16(af[m], bfr[n], acc[m][n], 0, 0, 0);
    }
    __syncthreads();
  }
  int row0 = blockIdx.x * 128 + wm * 64;
  int col0 = blockIdx.y * 128 + wn * 64;
  int g4 = (lane >> 4) << 2;
#pragma unroll
  for (int m = 0; m < 4; ++m) {
#pragma unroll
    for (int n = 0; n < 4; ++n) {
      int col = col0 + n * 16 + i15;
      float bv = bias[col];
      float v4[4];
#pragma unroll
      for (int r = 0; r < 4; ++r) v4[r] = acc[m][n][r] + bv;
      int rbase = row0 + m * 16 + g4;
      if constexpr (MODE == 0) {
        int sect = col / 768;            // 0=q 1=k 2=v
        int wi = col - sect * 768;
        int hh = wi >> 6, dd = wi & 63;
        int bb = rbase >> 11, tt = rbase & 2047;
        if (sect == 2) {
          s16x4 o4;
#pragma unroll
          for (int r = 0; r < 4; ++r) o4[r] = f2bf(v4[r]);
          *(s16x4*)(dv + ((size_t)(bb * H_ + hh) * D_ + dd) * T_ + tt) = o4;
        } else {
          short* dst = (sect == 0 ? dq : dk) + ((size_t)(bb * H_ + hh) * T_ + tt) * D_ + dd;
          float sc = sect == 0 ? 0.18033688f : 1.f;   // 0.125 * log2(e)
#pragma unroll
          for (int r = 0; r < 4; ++r) dst[(size_t)r * D_] = f2bf(v4[r] * sc);
        }
      } else {
#pragma unroll
        for (int r = 0; r < 4; ++r)
          ((short*)out)[(size_t)(rbase + r) * N + col] = f2bf(v4[r] > 0.f ? v4[r] : 0.f);
      }
    }
  }
}

// ---------- GEMM 64x128, BK=64, bias+residual -> f32 (out-proj & ff2) ----------
__global__ __launch_bounds__(128, 3) void gemm64_res(
    const short* __restrict__ A, const short* __restrict__ Bt,
    const float* __restrict__ bias, const float* __restrict__ res,
    float* __restrict__ out, int M, int N, int K) {
  __shared__ short As[2][64 * 32];
  __shared__ short Bs[2][128 * 32];
  int tid = threadIdx.x;
  int lane = tid & 63;
  int wn = tid >> 6;
  const short* Ab = A + (size_t)blockIdx.x * 64 * K;
  const short* Bb = Bt + (size_t)blockIdx.y * 128 * K;
  f32x4 acc[4][4] = {};
  int i15 = lane & 15, g8 = (lane >> 4) << 3;
  int nk = K >> 6;
  for (int kt = 0; kt < nk; ++kt) {
    int kof = kt << 6;
#pragma unroll
    for (int i = 0; i < 4; ++i) {
      int c = tid + i * 128;
      int pan = c >> 8, sp = c & 255;
      int row = sp >> 2, kk = ((sp & 3) << 3) + (pan << 5);
      __builtin_amdgcn_global_load_lds(
          (const __attribute__((address_space(1))) unsigned*)(Ab + (size_t)row * K + kof + kk),
          (__attribute__((address_space(3))) unsigned*)(&As[pan][sp * 8]), 16, 0, 0);
    }
#pragma unroll
    for (int i = 0; i < 8; ++i) {
      int c = tid + i * 128;
      int pan = c >> 9, sp = c & 511;
      int row = sp >> 2, kk = ((sp & 3) << 3) + (pan << 5);
      __builtin_amdgcn_global_load_lds(
          (const __attribute__((address_space(1))) unsigned*)(Bb + (size_t)row * K + kof + kk),
          (__attribute__((address_space(3))) unsigned*)(&Bs[pan][sp * 8]), 16, 0, 0);
    }
    __syncthreads();
#pragma unroll
    for (int h = 0; h < 2; ++h) {
      s16x8 af[4], bfr[4];
#pragma unroll
      for (int m = 0; m < 4; ++m)
        af[m] = *(const s16x8*)(&As[h][(m * 16 + i15) * 32 + g8]);
#pragma unroll
      for (int n = 0; n < 4; ++n)
        bfr[n] = *(const s16x8*)(&Bs[h][(wn * 64 + n * 16 + i15) * 32 + g8]);
#pragma unroll
      for (int m = 0; m < 4; ++m)
#pragma unroll
        for (int n = 0; n < 4; ++n)
          acc[m][n] = __builtin_amdgcn_mfma_f32_16x16x32_bf16(af[m], bfr[n], acc[m][n], 0, 0, 0);
    }
    __syncthreads();
  }
  int row0 = blockIdx.x * 64;
  int col0 = blockIdx.y * 128 + wn * 64;
  int g4 = (lane >> 4) << 2;
#pragma unroll
  for (int m = 0; m < 4; ++m) {
#pragma unroll
    for (int n = 0; n < 4; ++n) {
      int col = col0 + n * 16 + i15;
      float bv = bias[col];
      int rbase = row0 + m * 16 + g4;
#pragma unroll
      for (int r = 0; r < 4; ++r)
        out[(size_t)(rbase + r) * N + col] =
            acc[m][n][r] + bv + res[(size_t)(rbase + r) * N + col];
    }
  }
}

// ---------- causal flash attention: LDS-DMA staged + uniform pair blocks ----------
// 768 blocks x 4 waves = 3 blocks/CU resident (32KB LDS), 12 waves/CU for the
// WHOLE dispatch: block processes q-block pair (p, 31-p) sequentially ->
// uniform 33 tiles per block (R13's 1..32 triangular spread gave 25% occupancy
// with idle tails; VALU was the top pipe at 57% and needs ~3 waves/SIMD).
// Per tile: 16KB K/V staged once via global_load_lds DMA (TA fix, R13),
// double-buffered, one barrier/tile; all 4 waves compute every tile (16 rows
// each); finalize is register+shfl only (no cross-wave combine).
// Swizzle f(r)=(r&7)^((r&8)>>1), linear dest + inv-swz source + swz read.
// Q/K [B,H,T,D] (Q pre-scaled 0.125*log2e), VT [B,H,D,T] bf16 -> Ob [B,T,C].
__global__ __launch_bounds__(256) void attn_kernel(const short* __restrict__ Qb,
                                                   const short* __restrict__ Kb,
                                                   const short* __restrict__ VTb,
                                                   short* __restrict__ Ob) {
  __shared__ short Ks[2][4096];   // [64 keys][8 chunks x 8 shorts] swizzled
  __shared__ short Vs[2][4096];   // [64 d][8 chunks x 8 shorts] swizzled
  int i = blockIdx.x;
  int c = i & 7, j = i >> 3;
  int p = j & 15, gy = j >> 4;         // pair [0,16), head-group [0,6)
  int bh = c + (gy << 3);              // XCD(i)=i%8=c=bh%8: 6 heads/XCD in L2
  int bb = bh / H_, hh = bh - bb * H_;
  int tid = threadIdx.x, lane = tid & 63, wv = tid >> 6;
  const short* Qp = Qb + (size_t)bh * T_ * D_;
  const short* Kp = Kb + (size_t)bh * T_ * D_;
  const short* Vp = VTb + (size_t)bh * D_ * T_;
  int i15 = lane & 15, g = lane >> 4, g8 = g << 3;
  int keyA0 = ((i15 >> 2) << 3) + (i15 & 3);  // perm: A-row i -> key (i/4)*8+i%4
  int keyB0 = keyA0 + 4;
  int fA = (keyA0 & 7) ^ ((keyA0 & 8) >> 1);
  int fB = (keyB0 & 7) ^ ((keyB0 & 8) >> 1);
  int fV = (i15 & 7) ^ ((i15 & 8) >> 1);
  int oA[2], oB[2], oV[2];
#pragma unroll
  for (int h = 0; h < 2; ++h) {
    oA[h] = keyA0 * 64 + (((h * 4 + g) ^ fA) << 3);
    oB[h] = keyB0 * 64 + (((h * 4 + g) ^ fB) << 3);
    oV[h] = i15 * 64 + (((h * 4 + g) ^ fV) << 3);   // h = ks here
  }
  int n0 = p + 1;                      // tiles in sub0; sub1 = 32-p; total 33
  s16x8 qf0, qf1;
  f32x4 oacc[4] = {};
  float lsum = 0.f;
  int qrow = 0;

  auto loadQ = [&](int qb) {
    qrow = (qb << 6) + wv * 16 + i15;
    qf0 = *(const s16x8*)(Qp + (size_t)qrow * D_ + g8);
    qf1 = *(const s16x8*)(Qp + (size_t)qrow * D_ + 32 + g8);
  };
  auto stage = [&](int buf, int t) {
    int k0 = t << 6;
#pragma unroll
    for (int qq = 0; qq < 2; ++qq) {
      int m = tid + qq * 256;
      int r = m >> 3, cd = m & 7;
      int cs = cd ^ ((r & 7) ^ ((r & 8) >> 1));   // inverse swizzle on SOURCE
      __builtin_amdgcn_global_load_lds(
          (const __attribute__((address_space(1))) unsigned*)(Kp + (size_t)(k0 + r) * D_ + (cs << 3)),
          (__attribute__((address_space(3))) unsigned*)(&Ks[buf][m * 8]), 16, 0, 0);
      __builtin_amdgcn_global_load_lds(
          (const __attribute__((address_space(1))) unsigned*)(Vp + (size_t)r * T_ + k0 + (cs << 3)),
          (__attribute__((address_space(3))) unsigned*)(&Vs[buf][m * 8]), 16, 0, 0);
    }
  };
  auto finalize = [&]() {
    float l = lsum;
    l += __shfl_xor(l, 16);
    l += __shfl_xor(l, 32);
    float inv = 1.f / l;
    short* op = Ob + ((size_t)(bb * T_ + qrow)) * C_ + hh * D_ + (g << 2);
#pragma unroll
    for (int mt = 0; mt < 4; ++mt) {
      s16x4 o4;
#pragma unroll
      for (int r = 0; r < 4; ++r) o4[r] = f2bf(oacc[mt][r] * inv);
      *(s16x4*)(op + mt * 16) = o4;
    }
  };

  loadQ(p);
  stage(0, 0);
  __syncthreads();
  int cur = 0;
#pragma unroll 1
  for (int gt = 0; gt < 33; ++gt) {
    if (gt + 1 < 33) {
      int nkt = (gt + 1 < n0) ? (gt + 1) : (gt + 1 - n0);
      stage(cur ^ 1, nkt);
    }
    int kt = (gt < n0) ? gt : gt - n0;
    int nt = (gt < n0) ? n0 : 32 - p;
    bool diag = (kt == nt - 1);
    int k0 = kt << 6;
    const short* KB = &Ks[cur][0];
    const short* VB = &Vs[cur][0];
#pragma unroll
    for (int ks = 0; ks < 2; ++ks) {
      if (!(ks == 1 && diag && wv < 2)) {        // skip fully-masked group
        s16x8 ka0 = *(const s16x8*)(KB + (ks << 11) + oA[0]);
        s16x8 ka1 = *(const s16x8*)(KB + (ks << 11) + oA[1]);
        s16x8 kb0 = *(const s16x8*)(KB + (ks << 11) + oB[0]);
        s16x8 kb1 = *(const s16x8*)(KB + (ks << 11) + oB[1]);
        f32x4 sA = {}, sB = {};
        __builtin_amdgcn_s_setprio(1);
        sA = __builtin_amdgcn_mfma_f32_16x16x32_bf16(ka0, qf0, sA, 0, 0, 0);
        sA = __builtin_amdgcn_mfma_f32_16x16x32_bf16(ka1, qf1, sA, 0, 0, 0);
        sB = __builtin_amdgcn_mfma_f32_16x16x32_bf16(kb0, qf0, sB, 0, 0, 0);
        sB = __builtin_amdgcn_mfma_f32_16x16x32_bf16(kb1, qf1, sB, 0, 0, 0);
        __builtin_amdgcn_s_setprio(0);
        int kb = k0 + (ks << 5) + g8;
        float sa[8];
        bool needmask = diag && ((wv < 2) == (ks == 0));
        if (needmask) {
#pragma unroll
          for (int r = 0; r < 4; ++r) {
            sa[r]     = (kb + r     <= qrow) ? sA[r] : -1e30f;
            sa[4 + r] = (kb + 4 + r <= qrow) ? sB[r] : -1e30f;
          }
        } else {
#pragma unroll
          for (int r = 0; r < 4; ++r) { sa[r] = sA[r]; sa[4 + r] = sB[r]; }
        }
        float pv[8];
        float ps = 0.f;
#pragma unroll
        for (int r = 0; r < 8; ++r) {
          pv[r] = exp2f(sa[r]);
          ps += pv[r];
        }
        lsum += ps;
        union { unsigned u[4]; s16x8 v; } pf;
        pf.u[0] = pkbf2(pv[0], pv[1]);
        pf.u[1] = pkbf2(pv[2], pv[3]);
        pf.u[2] = pkbf2(pv[4], pv[5]);
        pf.u[3] = pkbf2(pv[6], pv[7]);
        s16x8 vf0 = *(const s16x8*)(VB + 0    + oV[ks]);
        s16x8 vf1 = *(const s16x8*)(VB + 1024 + oV[ks]);
        s16x8 vf2 = *(const s16x8*)(VB + 2048 + oV[ks]);
        s16x8 vf3 = *(const s16x8*)(VB + 3072 + oV[ks]);
        __builtin_amdgcn_s_setprio(1);
        oacc[0] = __builtin_amdgcn_mfma_f32_16x16x32_bf16(vf0, pf.v, oacc[0], 0, 0, 0);
        oacc[1] = __builtin_amdgcn_mfma_f32_16x16x32_bf16(vf1, pf.v, oacc[1], 0, 0, 0);
        oacc[2] = __builtin_amdgcn_mfma_f32_16x16x32_bf16(vf2, pf.v, oacc[2], 0, 0, 0);
        oacc[3] = __builtin_amdgcn_mfma_f32_16x16x32_bf16(vf3, pf.v, oacc[3], 0, 0, 0);
        __builtin_amdgcn_s_setprio(0);
      }
    }
    if (gt == n0 - 1) {                // sub0 complete: write it, start sub1
      finalize();
      loadQ(31 - p);
#pragma unroll
      for (int mt = 0; mt < 4; ++mt) oacc[mt] = f32x4{0.f, 0.f, 0.f, 0.f};
      lsum = 0.f;
    }
    __syncthreads();
    cur ^= 1;
  }
  finalize();
}

extern "C" void kernel_launch(void* const* d_in, const int* in_sizes, int n_in,
                              void* d_out, int out_size, void* d_ws, size_t ws_size,
                              hipStream_t stream) {
  const float* x     = (const float*)d_in[0];
  const float* ln1_w = (const float*)d_in[1];
  const float* ln1_b = (const float*)d_in[2];
  const float* qkv_w = (const float*)d_in[3];
  const float* qkv_b = (const float*)d_in[4];
  const float* out_w = (const float*)d_in[5];
  const float* out_b = (const float*)d_in[6];
  const float* ln2_w = (const float*)d_in[7];
  const float* ln2_b = (const float*)d_in[8];
  const float* ff1_w = (const float*)d_in[9];
  const float* ff1_b = (const float*)d_in[10];
  const float* ff2_w = (const float*)d_in[11];
  const float* ff2_b = (const float*)d_in[12];

  char* ws = (char*)d_ws;
  short* Wqkv = (short*)(ws + 0);                       // [2304,768]
  short* Wout = (short*)(ws + 3538944);                 // [768,768]
  short* Wff1 = (short*)(ws + 4718592);                 // [3072,768]
  short* Wff2 = (short*)(ws + 9437184);                 // [768,3072]
  short* Hbuf = (short*)(ws + 14155776);                // [8192,768] bf16
  short* Qb   = (short*)(ws + 26738688);                // [B,H,T,D] bf16
  short* Kb   = Qb + 6291456;
  short* VT   = Kb + 6291456;                           // [B,H,D,T] bf16 (V stored transposed)
  short* Ob   = VT + 6291456;                           // [B,T,C] bf16
  short* FFH  = Qb;                                     // alias: [8192,3072] bf16 (Q/K/V/O dead)
  float* xout = (float*)d_out;                          // also x1 residual buffer

  wconv<<<dim3(24, 72), 256, 0, stream>>>(qkv_w, Wqkv, 768, 2304);
  wconv<<<dim3(24, 24), 256, 0, stream>>>(out_w, Wout, 768, 768);
  wconv<<<dim3(24, 96), 256, 0, stream>>>(ff1_w, Wff1, 768, 3072);
  wconv<<<dim3(96, 24), 256, 0, stream>>>(ff2_w, Wff2, 3072, 768);

  ln_kernel<<<8192, 256, 0, stream>>>(x, ln1_w, ln1_b, Hbuf);
  gemm_bt<0><<<dim3(64, 18), 256, 0, stream>>>(Hbuf, Wqkv, qkv_b, nullptr, nullptr,
                                               Qb, Kb, VT, 8192, 2304, 768);
  attn_kernel<<<768, 256, 0, stream>>>(Qb, Kb, VT, Ob);
  gemm64_res<<<dim3(128, 6), 128, 0, stream>>>(Ob, Wout, out_b, x, xout, 8192, 768, 768);
  ln_kernel<<<8192, 256, 0, stream>>>(xout, ln2_w, ln2_b, Hbuf);
  gemm_bt<2><<<dim3(64, 24), 256, 0, stream>>>(Hbuf, Wff1, ff1_b, nullptr, FFH,
                                               nullptr, nullptr, nullptr, 8192, 3072, 768);
  gemm64_res<<<dim3(128, 6), 128, 0, stream>>>(FFH, Wff2, ff2_b, xout, xout, 8192, 768, 3072);
}